// Round 7
// baseline (212.385 us; speedup 1.0000x reference)
//
#include <hip/hip_runtime.h>

typedef _Float16 half_t;
typedef _Float16 half8 __attribute__((ext_vector_type(8)));
typedef _Float16 half4_t __attribute__((ext_vector_type(4)));
typedef _Float16 half2_t __attribute__((ext_vector_type(2)));
typedef float floatx4 __attribute__((ext_vector_type(4)));
typedef float floatx16 __attribute__((ext_vector_type(16)));
typedef unsigned int uint4v __attribute__((ext_vector_type(4)));
typedef unsigned int uint2v __attribute__((ext_vector_type(2)));

#define B_SZ 2
#define SEQ 2048
#define DIM_ 1024
#define NH 16
#define DH 64
#define ROWS (B_SZ * SEQ)   // 4096
#define NJS 2               // j-split ways; grid 32*16*NJS = 1024 blocks

// async global->LDS, 16B per lane; LDS dest = wave-uniform base + lane*16
__device__ __forceinline__ void gl2lds16(const void* g, void* l) {
  __builtin_amdgcn_global_load_lds((const __attribute__((address_space(1))) unsigned int*)g,
                                   (__attribute__((address_space(3))) unsigned int*)l, 16, 0, 0);
}

// exp2 (single v_exp_f32; log2(e) folded into q scale at GEMM epilogue)
__device__ __forceinline__ float fexp2(float x) {
#if __has_builtin(__builtin_amdgcn_exp2f)
  return __builtin_amdgcn_exp2f(x);
#else
  return __expf(x * 0.6931471805599453f);
#endif
}

__device__ __forceinline__ unsigned cvtpk_u32(float a, float b) {
#if __has_builtin(__builtin_amdgcn_cvt_pkrtz)
  return __builtin_bit_cast(unsigned, __builtin_amdgcn_cvt_pkrtz(a, b));
#else
  half2_t h; h.x = (half_t)a; h.y = (half_t)b;
  return __builtin_bit_cast(unsigned, h);
#endif
}

// one kernel converts x, w_qkv, w_proj (contiguous in ws) fp32->fp16
__global__ __launch_bounds__(256) void convert_all(const float4* __restrict__ x,
                                                   const float4* __restrict__ wq,
                                                   const float4* __restrict__ wp,
                                                   half4_t* __restrict__ dst,
                                                   int nx, int nq, int np) {
  int i = blockIdx.x * blockDim.x + threadIdx.x;
  float4 v;
  if (i < nx) v = x[i];
  else if (i < nx + nq) v = wq[i - nx];
  else if (i < nx + nq + np) v = wp[i - nx - nq];
  else return;
  half4_t h;
  h.x = (half_t)v.x; h.y = (half_t)v.y; h.z = (half_t)v.z; h.w = (half_t)v.w;
  dst[i] = h;
}

// C = A[4096][1024] @ Bt[N][1024]^T. 32x32x16 MFMA, BK=64, 128xBN tile, 4 waves.
// MODE 0 (BN=128): qkv epilogue. MODE 1 (BN=64): proj fp32 out.
template <int MODE, int BN>
__global__ __launch_bounds__(256) void gemm32(const half_t* __restrict__ A,
                                              const half_t* __restrict__ Bt,
                                              half_t* __restrict__ q16,
                                              half_t* __restrict__ k16,
                                              half_t* __restrict__ vT16,
                                              float* __restrict__ outp) {
  constexpr int K = 1024;
  constexpr int NT = BN / 64;  // 32x32 n-tiles per wave
  __shared__ __align__(16) half_t a_lds[128 * 64];
  __shared__ __align__(16) half_t b_lds[BN * 64];
  const int t = threadIdx.x;
  const int wave = t >> 6, lane = t & 63;
  const int l31 = lane & 31, hw = lane >> 5;
  const int wm = wave >> 1, wn = wave & 1;
  const int row0 = blockIdx.y * 128, col0 = blockIdx.x * BN;

  floatx16 acc[2][NT];
#pragma unroll
  for (int i = 0; i < 2; ++i)
#pragma unroll
    for (int j = 0; j < NT; ++j)
#pragma unroll
      for (int r = 0; r < 16; ++r) acc[i][j][r] = 0.f;

  for (int k0 = 0; k0 < K; k0 += 64) {
    // A: 128 rows x 8 chunks(16B) = 1024 segs, 4/thread
#pragma unroll
    for (int hi = 0; hi < 4; ++hi) {
      int s = t + hi * 256;
      int row = s >> 3, c = s & 7;
      int sc = c ^ (row & 7);
      gl2lds16(A + (size_t)(row0 + row) * K + (k0 + sc * 8), a_lds + (wave * 64 + hi * 256) * 8);
    }
    // B: BN rows x 8 chunks
#pragma unroll
    for (int hi = 0; hi < BN / 32; ++hi) {
      int s = t + hi * 256;
      int row = s >> 3, c = s & 7;
      int sc = c ^ (row & 7);
      gl2lds16(Bt + (size_t)(col0 + row) * K + (k0 + sc * 8), b_lds + (wave * 64 + hi * 256) * 8);
    }
    __syncthreads();
    half8 af[2][4], bf[NT][4];
#pragma unroll
    for (int mt = 0; mt < 2; ++mt) {
      int row = wm * 64 + mt * 32 + l31;
#pragma unroll
      for (int kf = 0; kf < 4; ++kf)
        af[mt][kf] = *(const half8*)(a_lds + row * 64 + ((kf * 2 + hw) ^ (row & 7)) * 8);
    }
#pragma unroll
    for (int nt = 0; nt < NT; ++nt) {
      int row = wn * (BN / 2) + nt * 32 + l31;
#pragma unroll
      for (int kf = 0; kf < 4; ++kf)
        bf[nt][kf] = *(const half8*)(b_lds + row * 64 + ((kf * 2 + hw) ^ (row & 7)) * 8);
    }
#pragma unroll
    for (int kf = 0; kf < 4; ++kf)
#pragma unroll
      for (int mt = 0; mt < 2; ++mt)
#pragma unroll
        for (int nt = 0; nt < NT; ++nt)
          acc[mt][nt] =
              __builtin_amdgcn_mfma_f32_32x32x16_f16(af[mt][kf], bf[nt][kf], acc[mt][nt], 0, 0, 0);
    __syncthreads();
  }

  // C/D 32x32 mapping: col = lane&31, row = (r&3) + 8*(r>>2) + 4*(lane>>5)
  if (MODE == 0) {
    const int which = col0 >> 10;
#pragma unroll
    for (int mt = 0; mt < 2; ++mt)
#pragma unroll
      for (int nt = 0; nt < NT; ++nt) {
        int growb = row0 + wm * 64 + mt * 32;
        int gcol = col0 + wn * (BN / 2) + nt * 32 + l31;
        int hc = gcol & 1023, h = hc >> 6, d = hc & 63;
        if (which == 2) {
#pragma unroll
          for (int rq = 0; rq < 4; ++rq) {
            int grow = growb + 8 * rq + 4 * hw;
            int b = grow >> 11, n0 = grow & 2047;
            int bh = b * NH + h;
            half4_t h4;
            h4.x = (half_t)acc[mt][nt][rq * 4 + 0];
            h4.y = (half_t)acc[mt][nt][rq * 4 + 1];
            h4.z = (half_t)acc[mt][nt][rq * 4 + 2];
            h4.w = (half_t)acc[mt][nt][rq * 4 + 3];
            *(half4_t*)(vT16 + ((size_t)bh * DH + d) * SEQ + n0) = h4;
          }
        } else {
#pragma unroll
          for (int r = 0; r < 16; ++r) {
            int grow = growb + (r & 3) + 8 * (r >> 2) + 4 * hw;
            int b = grow >> 11, n = grow & 2047;
            int bh = b * NH + h;
            float v = acc[mt][nt][r];
            if (which == 0)
              q16[((size_t)bh * SEQ + n) * DH + d] =
                  (half_t)(v * 0.1803368801111204f);  // fold SCALE * log2(e)
            else
              k16[((size_t)bh * SEQ + n) * DH + d] = (half_t)v;
          }
        }
      }
  } else {
#pragma unroll
    for (int mt = 0; mt < 2; ++mt)
#pragma unroll
      for (int nt = 0; nt < NT; ++nt) {
        int growb = row0 + wm * 64 + mt * 32;
        int gcol = col0 + wn * (BN / 2) + nt * 32 + l31;
#pragma unroll
        for (int r = 0; r < 16; ++r) {
          int grow = growb + (r & 3) + 8 * (r >> 2) + 4 * hw;
          outp[(size_t)grow * DIM_ + gcol] = acc[mt][nt][r];
        }
      }
  }
}

// Flash attention pass 1, all-32x32x16. Block = 4 waves x 32 q = 128 q-rows.
// K is LDS-staged (double-buffered, 16 KB; amortized across 4 waves). V is
// read DIRECTLY from global (vT16 L2/L3-resident; per-lane row base + uniform
// offsets) -- halves the LDS-pipe traffic that was the per-CU bottleneck.
// V loads issued right after QK MFMAs; L2 latency lands under the exp chain.
__global__ __launch_bounds__(256, 3) void attn_p1(const half_t* __restrict__ q16,
                                                  const half_t* __restrict__ k16,
                                                  const half_t* __restrict__ vT16,
                                                  half_t* __restrict__ opart,
                                                  float* __restrict__ psums) {
  __shared__ __align__(16) half_t k_lds[2][64 * 64];  // [j][d], dbuf

  const int t = threadIdx.x;
  const int wave = t >> 6, lane = t & 63;
  const int l31 = lane & 31, hw = lane >> 5;
  const int blk = blockIdx.x;
  const int js = blk & (NJS - 1), qt = (blk / NJS) & 15, bh = blk / (NJS * 16);
  const half_t* qp = q16 + (size_t)bh * SEQ * DH;
  const half_t* kp = k16 + (size_t)bh * SEQ * DH;
  const half_t* vp = vT16 + (size_t)bh * DH * SEQ;
  const int q0w = qt * 128 + wave * 32;
  const int jbase = js * (SEQ / NJS);
  constexpr int NJT = (SEQ / NJS) / 64;  // 16

  // K staging: 512 segs of 16B (64 rows x 8 chunks), chunk XOR row&7
  const int s0 = t, s1 = t + 256;
  const int r0_ = s0 >> 3, c0_ = (s0 & 7) ^ (r0_ & 7);
  const int r1_ = s1 >> 3, c1_ = (s1 & 7) ^ (r1_ & 7);

  // per-lane V row base: lane l31 covers d = dt*32 + l31
  const half_t* vrow = vp + (size_t)l31 * SEQ + hw * 8;

  // Q fragments, B-operand 32x32x16: col = l31 = q, k = kf*16 + hw*8 + i
  half8 qf[4];
#pragma unroll
  for (int kf = 0; kf < 4; ++kf)
    qf[kf] = *(const half8*)(qp + (size_t)(q0w + l31) * DH + kf * 16 + hw * 8);

  floatx16 o[2];  // [d-tile]; C/D: col=l31=d, row=(r&3)+8(r>>2)+4hw = q
#pragma unroll
  for (int i = 0; i < 2; ++i)
#pragma unroll
    for (int r = 0; r < 16; ++r) o[i][r] = 0.f;
  float psum = 0.f;

  // prologue: stage K tile jbase into buffer 0
  gl2lds16(kp + (size_t)(jbase + r0_) * DH + c0_ * 8, &k_lds[0][(wave * 64) * 8]);
  gl2lds16(kp + (size_t)(jbase + r1_) * DH + c1_ * 8, &k_lds[0][(wave * 64 + 256) * 8]);

  int cur = 0;
  for (int jt = 0; jt < NJT; ++jt) {
    __syncthreads();  // publishes k_lds[cur], protects k_lds[cur^1]

    if (jt + 1 < NJT) {
      const int j0 = jbase + (jt + 1) * 64, nb = cur ^ 1;
      gl2lds16(kp + (size_t)(j0 + r0_) * DH + c0_ * 8, &k_lds[nb][(wave * 64) * 8]);
      gl2lds16(kp + (size_t)(j0 + r1_) * DH + c1_ * 8, &k_lds[nb][(wave * 64 + 256) * 8]);
    }

    const half_t* kl = k_lds[cur];
    const int jcur = jbase + jt * 64;

    // S^T[j 64][q 32]: A = K (m=j, 2 tiles), B = Q. 8 MFMAs of 32x32x16.
    floatx16 st[2];
#pragma unroll
    for (int m = 0; m < 2; ++m)
#pragma unroll
      for (int r = 0; r < 16; ++r) st[m][r] = 0.f;
    __builtin_amdgcn_s_setprio(1);
#pragma unroll
    for (int kf = 0; kf < 4; ++kf)
#pragma unroll
      for (int m = 0; m < 2; ++m) {
        int row = m * 32 + l31;  // j
        half8 kb = *(const half8*)(kl + row * 64 + ((kf * 2 + hw) ^ (row & 7)) * 8);
        st[m] = __builtin_amdgcn_mfma_f32_32x32x16_f16(kb, qf[kf], st[m], 0, 0, 0);
      }
    __builtin_amdgcn_s_setprio(0);

    // V B-frags direct from global (L2): row d = dt*32+l31, k = j = ks*16+hw*8+i.
    // Issued before the exp chain; latency hides under it.
    half8 vreg[4][2];
#pragma unroll
    for (int ks = 0; ks < 4; ++ks)
#pragma unroll
      for (int dt = 0; dt < 2; ++dt)
        vreg[ks][dt] = *(const half8*)(vrow + (size_t)dt * 32 * SEQ + jcur + ks * 16);

    // exp2 -> psum + natural-k PV A-frags (cvt_pkrtz + permlane32_swap)
    half8 pa[4];
#pragma unroll
    for (int ks = 0; ks < 4; ++ks) {
      const int m = ks >> 1, rb = (ks & 1) * 8;
      float p0 = fexp2(st[m][rb + 0]);
      float p1 = fexp2(st[m][rb + 1]);
      float p2 = fexp2(st[m][rb + 2]);
      float p3 = fexp2(st[m][rb + 3]);
      float p4 = fexp2(st[m][rb + 4]);
      float p5 = fexp2(st[m][rb + 5]);
      float p6 = fexp2(st[m][rb + 6]);
      float p7 = fexp2(st[m][rb + 7]);
      psum += ((p0 + p1) + (p2 + p3)) + ((p4 + p5) + (p6 + p7));
      unsigned uA = cvtpk_u32(p0, p1);
      unsigned uB = cvtpk_u32(p2, p3);
      unsigned uC = cvtpk_u32(p4, p5);
      unsigned uD = cvtpk_u32(p6, p7);
#if __has_builtin(__builtin_amdgcn_permlane32_swap)
      uint2v sAC = __builtin_bit_cast(uint2v, __builtin_amdgcn_permlane32_swap(uA, uC, false, false));
      uint2v sBD = __builtin_bit_cast(uint2v, __builtin_amdgcn_permlane32_swap(uB, uD, false, false));
      uint4v u;
      u.x = sAC.x; u.y = sBD.x; u.z = sAC.y; u.w = sBD.y;
#else
      unsigned xA = (unsigned)__shfl_xor((int)uA, 32, 64);
      unsigned xB = (unsigned)__shfl_xor((int)uB, 32, 64);
      unsigned xC = (unsigned)__shfl_xor((int)uC, 32, 64);
      unsigned xD = (unsigned)__shfl_xor((int)uD, 32, 64);
      uint4v u;
      u.x = hw ? xC : uA;
      u.y = hw ? xD : uB;
      u.z = hw ? uC : xA;
      u.w = hw ? uD : xB;
#endif
      pa[ks] = __builtin_bit_cast(half8, u);
    }

    // O[q 32][d 64] += P@V. 8 MFMAs using vreg.
    __builtin_amdgcn_s_setprio(1);
#pragma unroll
    for (int ks = 0; ks < 4; ++ks)
#pragma unroll
      for (int dt = 0; dt < 2; ++dt)
        o[dt] = __builtin_amdgcn_mfma_f32_32x32x16_f16(pa[ks], vreg[ks][dt], o[dt], 0, 0, 0);
    __builtin_amdgcn_s_setprio(0);
    cur ^= 1;
  }

  // psum: lane holds sum over its half's j for q = q0w + l31
  psum += __shfl_xor(psum, 32, 64);
  if (hw == 0) psums[((size_t)(js * 32 + bh)) * SEQ + q0w + l31] = psum;

  // unnormalized O -> fp16 partials; q = q0w + (r&3)+8(r>>2)+4hw, d = dt*32+l31
#pragma unroll
  for (int dt = 0; dt < 2; ++dt)
#pragma unroll
    for (int r = 0; r < 16; ++r) {
      int n = q0w + (r & 3) + 8 * (r >> 2) + 4 * hw;
      opart[((size_t)(js * 32 + bh) * SEQ + n) * DH + dt * 32 + l31] = (half_t)o[dt][r];
    }
}

// combine: out = (sum_js O_js) * softmax(head_w)[h] / (sum_js ps_js), fp16 attn16
__global__ __launch_bounds__(256) void combine(const half_t* __restrict__ opart,
                                               const float* __restrict__ psums,
                                               const float* __restrict__ head_w,
                                               half_t* __restrict__ attn16) {
  int idx = blockIdx.x * blockDim.x + threadIdx.x;  // 1M threads, 4 d each
  int d4 = idx & 15, n = (idx >> 4) & 2047, bh = idx >> 15;
  int h = bh & 15, b = bh >> 4;
  const size_t jstr = (size_t)32 * SEQ * DH;
  size_t off = ((size_t)bh * SEQ + n) * DH + d4 * 4;

  float sx = 0.f, sy = 0.f, sz = 0.f, sw2 = 0.f, ps = 0.f;
#pragma unroll
  for (int js = 0; js < NJS; ++js) {
    half4_t ov = *(const half4_t*)(opart + js * jstr + off);
    sx += (float)ov.x; sy += (float)ov.y; sz += (float)ov.z; sw2 += (float)ov.w;
    ps += psums[(size_t)js * 32 * SEQ + (size_t)bh * SEQ + n];
  }

  float mw = head_w[0];
#pragma unroll
  for (int i = 1; i < NH; ++i) mw = fmaxf(mw, head_w[i]);
  float sw = 0.f;
#pragma unroll
  for (int i = 0; i < NH; ++i) sw += __expf(head_w[i] - mw);
  float hwv = __expf(head_w[h] - mw) / sw;

  float scl = hwv / ps;
  half4_t r;
  r.x = (half_t)(sx * scl);
  r.y = (half_t)(sy * scl);
  r.z = (half_t)(sz * scl);
  r.w = (half_t)(sw2 * scl);
  *(half4_t*)(attn16 + ((size_t)(b * SEQ + n)) * DIM_ + h * DH + d4 * 4) = r;
}

extern "C" void kernel_launch(void* const* d_in, const int* in_sizes, int n_in,
                              void* d_out, int out_size, void* d_ws, size_t ws_size,
                              hipStream_t stream) {
  const float* x = (const float*)d_in[0];
  const float* w_qkv = (const float*)d_in[1];
  const float* w_proj = (const float*)d_in[2];
  const float* head_w = (const float*)d_in[3];
  float* out = (float*)d_out;

  half_t* x16 = (half_t*)d_ws;                          // 4096*1024
  half_t* wq16 = x16 + (size_t)ROWS * DIM_;             // 3072*1024
  half_t* wp16 = wq16 + (size_t)3 * DIM_ * DIM_;        // 1024*1024
  half_t* q16 = wp16 + (size_t)DIM_ * DIM_;             // [B,H,N,Dh] (scaled by 0.125*log2e)
  half_t* k16 = q16 + (size_t)ROWS * DIM_;              // [B,H,N,Dh]
  half_t* vT16 = k16 + (size_t)ROWS * DIM_;             // [B,H,Dh,N]
  half_t* attn16 = vT16 + (size_t)ROWS * DIM_;          // [B*N, DIM]
  half_t* opart = attn16 + (size_t)ROWS * DIM_;         // [NJS][32][2048][64] fp16
  float* psums = (float*)(opart + (size_t)NJS * 32 * SEQ * DH);  // [NJS][32][2048] f32

  const int nx = ROWS * DIM_ / 4, nq = 3 * DIM_ * DIM_ / 4, np = DIM_ * DIM_ / 4;
  convert_all<<<(nx + nq + np) / 256, 256, 0, stream>>>((const float4*)x, (const float4*)w_qkv,
                                                        (const float4*)w_proj, (half4_t*)x16,
                                                        nx, nq, np);

  gemm32<0, 128><<<dim3(24, 32), 256, 0, stream>>>(x16, wq16, q16, k16, vT16, nullptr);
  attn_p1<<<32 * 16 * NJS, 256, 0, stream>>>(q16, k16, vT16, opart, psums);
  combine<<<(32 * SEQ * DH / 4) / 256, 256, 0, stream>>>(opart, psums, head_w, attn16);
  gemm32<1, 64><<<dim3(16, 32), 256, 0, stream>>>(attn16, wp16, nullptr, nullptr, nullptr, out);
}

// Round 8
// 189.938 us; speedup vs baseline: 1.1182x; 1.1182x over previous
//
#include <hip/hip_runtime.h>

typedef _Float16 half_t;
typedef _Float16 half8 __attribute__((ext_vector_type(8)));
typedef _Float16 half4_t __attribute__((ext_vector_type(4)));
typedef _Float16 half2_t __attribute__((ext_vector_type(2)));
typedef float floatx4 __attribute__((ext_vector_type(4)));
typedef float floatx16 __attribute__((ext_vector_type(16)));
typedef unsigned int uint4v __attribute__((ext_vector_type(4)));
typedef unsigned int uint2v __attribute__((ext_vector_type(2)));

#define B_SZ 2
#define SEQ 2048
#define DIM_ 1024
#define NH 16
#define DH 64
#define ROWS (B_SZ * SEQ)   // 4096
#define NJS 2               // j-split ways; attn grid 32*16*NJS = 1024 blocks

// async global->LDS, 16B per lane; LDS dest = wave-uniform base + lane*16
__device__ __forceinline__ void gl2lds16(const void* g, void* l) {
  __builtin_amdgcn_global_load_lds((const __attribute__((address_space(1))) unsigned int*)g,
                                   (__attribute__((address_space(3))) unsigned int*)l, 16, 0, 0);
}

// exp2 (single v_exp_f32; log2(e) folded into q scale at GEMM epilogue)
__device__ __forceinline__ float fexp2(float x) {
#if __has_builtin(__builtin_amdgcn_exp2f)
  return __builtin_amdgcn_exp2f(x);
#else
  return __expf(x * 0.6931471805599453f);
#endif
}

__device__ __forceinline__ unsigned cvtpk_u32(float a, float b) {
#if __has_builtin(__builtin_amdgcn_cvt_pkrtz)
  return __builtin_bit_cast(unsigned, __builtin_amdgcn_cvt_pkrtz(a, b));
#else
  half2_t h; h.x = (half_t)a; h.y = (half_t)b;
  return __builtin_bit_cast(unsigned, h);
#endif
}

__device__ __forceinline__ float frcp(float x) {
#if __has_builtin(__builtin_amdgcn_rcpf)
  return __builtin_amdgcn_rcpf(x);
#else
  return 1.f / x;
#endif
}

// one kernel converts x, w_qkv, w_proj (contiguous in ws) fp32->fp16
__global__ __launch_bounds__(256) void convert_all(const float4* __restrict__ x,
                                                   const float4* __restrict__ wq,
                                                   const float4* __restrict__ wp,
                                                   half4_t* __restrict__ dst,
                                                   int nx, int nq, int np) {
  int i = blockIdx.x * blockDim.x + threadIdx.x;
  float4 v;
  if (i < nx) v = x[i];
  else if (i < nx + nq) v = wq[i - nx];
  else if (i < nx + nq + np) v = wp[i - nx - nq];
  else return;
  half4_t h;
  h.x = (half_t)v.x; h.y = (half_t)v.y; h.z = (half_t)v.z; h.w = (half_t)v.w;
  dst[i] = h;
}

// C = A[4096][1024] @ Bt[N][1024]^T. 32x32x16 MFMA, BK=64, 128xBN tile, 4 waves.
// MODE 0 (BN=128): A = x16 via gl2lds16; qkv scatter epilogue.
// MODE 2 (BN=64):  A = normalize(opart0+opart1) fused in staging (combine
//   folded in: BK=64=DH so each K-step is one head h=k0>>6; scl=4096*hwv/ps in
//   fp16, epilogue multiplies by 2^-12); fp32 out.
// Both: XCD-aware bijective block swizzle (grid %8 == 0).
template <int MODE, int BN>
__global__ __launch_bounds__(256) void gemm32(const half_t* __restrict__ A,
                                              const half_t* __restrict__ Bt,
                                              half_t* __restrict__ q16,
                                              half_t* __restrict__ k16,
                                              half_t* __restrict__ vT16,
                                              float* __restrict__ outp,
                                              const half_t* __restrict__ opart,
                                              const float* __restrict__ psums,
                                              const float* __restrict__ head_w) {
  constexpr int K = 1024;
  constexpr int NT = BN / 64;  // 32x32 n-tiles per wave
  __shared__ __align__(16) half_t a_lds[128 * 64];
  __shared__ __align__(16) half_t b_lds[BN * 64];
  const int t = threadIdx.x;
  const int wave = t >> 6, lane = t & 63;
  const int l31 = lane & 31, hw = lane >> 5;
  const int wm = wave >> 1, wn = wave & 1;

  // XCD swizzle: lin -> (xcd chunk); grids are 768 / 512, both % 8 == 0
  const int lin = blockIdx.y * gridDim.x + blockIdx.x;
  const int cpx = (gridDim.x * gridDim.y) >> 3;
  const int nl = (lin & 7) * cpx + (lin >> 3);
  const int bx = nl % gridDim.x, by = nl / gridDim.x;
  const int row0 = by * 128, col0 = bx * BN;

  // MODE2: head_w softmax prelude (per-thread, trivial)
  float mw = 0.f, swd = 0.f;
  if constexpr (MODE == 2) {
    mw = head_w[0];
#pragma unroll
    for (int i = 1; i < NH; ++i) mw = fmaxf(mw, head_w[i]);
#pragma unroll
    for (int i = 0; i < NH; ++i) swd += __expf(head_w[i] - mw);
  }
  const size_t OJSTR = (size_t)32 * SEQ * DH;
  const size_t PSJ = (size_t)32 * SEQ;

  floatx16 acc[2][NT];
#pragma unroll
  for (int i = 0; i < 2; ++i)
#pragma unroll
    for (int j = 0; j < NT; ++j)
#pragma unroll
      for (int r = 0; r < 16; ++r) acc[i][j][r] = 0.f;

  for (int k0 = 0; k0 < K; k0 += 64) {
    if constexpr (MODE != 2) {
      // A: 128 rows x 8 chunks(16B) = 1024 segs, 4/thread, async
#pragma unroll
      for (int hi = 0; hi < 4; ++hi) {
        int s = t + hi * 256;
        int row = s >> 3, c = s & 7;
        int sc = c ^ (row & 7);
        gl2lds16(A + (size_t)(row0 + row) * K + (k0 + sc * 8), a_lds + (wave * 64 + hi * 256) * 8);
      }
    } else {
      // fused combine: A[row][k0+d] = (opart0+opart1)(bh,n,d) * (4096*hwv/ps)
      const int h = k0 >> 6;
      const float hs = __expf(head_w[h] - mw) * 4096.f / swd;
#pragma unroll
      for (int hi = 0; hi < 4; ++hi) {
        int s = t + hi * 256;
        int row = s >> 3, c = s & 7;
        int sc = c ^ (row & 7);
        int grow = row0 + row;
        int b = grow >> 11, n = grow & 2047;
        int bh = b * NH + h;
        size_t obase = ((size_t)bh * SEQ + n) * DH + sc * 8;
        half8 o0 = *(const half8*)(opart + obase);
        half8 o1 = *(const half8*)(opart + OJSTR + obase);
        float ps = psums[(size_t)bh * SEQ + n] + psums[PSJ + (size_t)bh * SEQ + n];
        half_t sclh = (half_t)(hs * frcp(ps));
        half8 r = (o0 + o1) * sclh;
        *(half8*)(a_lds + (size_t)s * 8) = r;
      }
    }
    // B: BN rows x 8 chunks
#pragma unroll
    for (int hi = 0; hi < BN / 32; ++hi) {
      int s = t + hi * 256;
      int row = s >> 3, c = s & 7;
      int sc = c ^ (row & 7);
      gl2lds16(Bt + (size_t)(col0 + row) * K + (k0 + sc * 8), b_lds + (wave * 64 + hi * 256) * 8);
    }
    __syncthreads();
    half8 af[2][4], bf[NT][4];
#pragma unroll
    for (int mt = 0; mt < 2; ++mt) {
      int row = wm * 64 + mt * 32 + l31;
#pragma unroll
      for (int kf = 0; kf < 4; ++kf)
        af[mt][kf] = *(const half8*)(a_lds + row * 64 + ((kf * 2 + hw) ^ (row & 7)) * 8);
    }
#pragma unroll
    for (int nt = 0; nt < NT; ++nt) {
      int row = wn * (BN / 2) + nt * 32 + l31;
#pragma unroll
      for (int kf = 0; kf < 4; ++kf)
        bf[nt][kf] = *(const half8*)(b_lds + row * 64 + ((kf * 2 + hw) ^ (row & 7)) * 8);
    }
#pragma unroll
    for (int kf = 0; kf < 4; ++kf)
#pragma unroll
      for (int mt = 0; mt < 2; ++mt)
#pragma unroll
        for (int nt = 0; nt < NT; ++nt)
          acc[mt][nt] =
              __builtin_amdgcn_mfma_f32_32x32x16_f16(af[mt][kf], bf[nt][kf], acc[mt][nt], 0, 0, 0);
    __syncthreads();
  }

  // C/D 32x32 mapping: col = lane&31, row = (r&3) + 8*(r>>2) + 4*(lane>>5)
  if (MODE == 0) {
    const int which = col0 >> 10;
#pragma unroll
    for (int mt = 0; mt < 2; ++mt)
#pragma unroll
      for (int nt = 0; nt < NT; ++nt) {
        int growb = row0 + wm * 64 + mt * 32;
        int gcol = col0 + wn * (BN / 2) + nt * 32 + l31;
        int hc = gcol & 1023, h = hc >> 6, d = hc & 63;
        if (which == 2) {
#pragma unroll
          for (int rq = 0; rq < 4; ++rq) {
            int grow = growb + 8 * rq + 4 * hw;
            int b = grow >> 11, n0 = grow & 2047;
            int bh = b * NH + h;
            half4_t h4;
            h4.x = (half_t)acc[mt][nt][rq * 4 + 0];
            h4.y = (half_t)acc[mt][nt][rq * 4 + 1];
            h4.z = (half_t)acc[mt][nt][rq * 4 + 2];
            h4.w = (half_t)acc[mt][nt][rq * 4 + 3];
            *(half4_t*)(vT16 + ((size_t)bh * DH + d) * SEQ + n0) = h4;
          }
        } else {
#pragma unroll
          for (int r = 0; r < 16; ++r) {
            int grow = growb + (r & 3) + 8 * (r >> 2) + 4 * hw;
            int b = grow >> 11, n = grow & 2047;
            int bh = b * NH + h;
            float v = acc[mt][nt][r];
            if (which == 0)
              q16[((size_t)bh * SEQ + n) * DH + d] =
                  (half_t)(v * 0.1803368801111204f);  // fold SCALE * log2(e)
            else
              k16[((size_t)bh * SEQ + n) * DH + d] = (half_t)v;
          }
        }
      }
  } else {
    constexpr float OSCL = 1.f / 4096.f;  // undo the 4096 in scl
#pragma unroll
    for (int mt = 0; mt < 2; ++mt)
#pragma unroll
      for (int nt = 0; nt < NT; ++nt) {
        int growb = row0 + wm * 64 + mt * 32;
        int gcol = col0 + wn * (BN / 2) + nt * 32 + l31;
#pragma unroll
        for (int r = 0; r < 16; ++r) {
          int grow = growb + (r & 3) + 8 * (r >> 2) + 4 * hw;
          outp[(size_t)grow * DIM_ + gcol] = acc[mt][nt][r] * OSCL;
        }
      }
  }
}

// Flash attention pass 1, all-32x32x16. Block = 4 waves x 32 q = 128 q-rows;
// j-slice SEQ/NJS. K,V both LDS-staged (double-buffered). S^T = mfma(K,Q):
// lane l31 = q. PV A-frags built in NATURAL k-order via cvt_pkrtz +
// permlane32_swap; V B-frags natural b128. (R4 config: NJS=2, bounds(256,3).)
__global__ __launch_bounds__(256, 3) void attn_p1(const half_t* __restrict__ q16,
                                                  const half_t* __restrict__ k16,
                                                  const half_t* __restrict__ vT16,
                                                  half_t* __restrict__ opart,
                                                  float* __restrict__ psums) {
  __shared__ __align__(16) half_t k_lds[2][64 * 64];  // [j][d]
  __shared__ __align__(16) half_t v_lds[2][64 * 64];  // vT: [d][j]

  const int t = threadIdx.x;
  const int wave = t >> 6, lane = t & 63;
  const int l31 = lane & 31, hw = lane >> 5;
  const int blk = blockIdx.x;
  const int js = blk & (NJS - 1), qt = (blk / NJS) & 15, bh = blk / (NJS * 16);
  const half_t* qp = q16 + (size_t)bh * SEQ * DH;
  const half_t* kp = k16 + (size_t)bh * SEQ * DH;
  const half_t* vp = vT16 + (size_t)bh * DH * SEQ;
  const int q0w = qt * 128 + wave * 32;
  const int jbase = js * (SEQ / NJS);
  constexpr int NJT = (SEQ / NJS) / 64;  // 16

  // staging offsets: 512 segs of 16B (64 rows x 8 chunks), chunk XOR row&7
  const int s0 = t, s1 = t + 256;
  const int r0_ = s0 >> 3, c0_ = (s0 & 7) ^ (r0_ & 7);
  const int r1_ = s1 >> 3, c1_ = (s1 & 7) ^ (r1_ & 7);

  // Q fragments, B-operand 32x32x16: col = l31 = q, k = kf*16 + hw*8 + i
  half8 qf[4];
#pragma unroll
  for (int kf = 0; kf < 4; ++kf)
    qf[kf] = *(const half8*)(qp + (size_t)(q0w + l31) * DH + kf * 16 + hw * 8);

  floatx16 o[2];  // [d-tile]; C/D: col=l31=d, row=(r&3)+8(r>>2)+4hw = q
#pragma unroll
  for (int i = 0; i < 2; ++i)
#pragma unroll
    for (int r = 0; r < 16; ++r) o[i][r] = 0.f;
  float psum = 0.f;

  // prologue: stage tile jbase into buffer 0
  gl2lds16(kp + (size_t)(jbase + r0_) * DH + c0_ * 8, &k_lds[0][(wave * 64) * 8]);
  gl2lds16(vp + (size_t)r0_ * SEQ + jbase + c0_ * 8, &v_lds[0][(wave * 64) * 8]);
  gl2lds16(kp + (size_t)(jbase + r1_) * DH + c1_ * 8, &k_lds[0][(wave * 64 + 256) * 8]);
  gl2lds16(vp + (size_t)r1_ * SEQ + jbase + c1_ * 8, &v_lds[0][(wave * 64 + 256) * 8]);

  int cur = 0;
  for (int jt = 0; jt < NJT; ++jt) {
    __syncthreads();  // publishes buf[cur], protects buf[cur^1]

    if (jt + 1 < NJT) {
      const int j0 = jbase + (jt + 1) * 64, nb = cur ^ 1;
      gl2lds16(kp + (size_t)(j0 + r0_) * DH + c0_ * 8, &k_lds[nb][(wave * 64) * 8]);
      gl2lds16(vp + (size_t)r0_ * SEQ + j0 + c0_ * 8, &v_lds[nb][(wave * 64) * 8]);
      gl2lds16(kp + (size_t)(j0 + r1_) * DH + c1_ * 8, &k_lds[nb][(wave * 64 + 256) * 8]);
      gl2lds16(vp + (size_t)r1_ * SEQ + j0 + c1_ * 8, &v_lds[nb][(wave * 64 + 256) * 8]);
    }

    const half_t* kl = k_lds[cur];
    const half_t* vl = v_lds[cur];

    // S^T[j 64][q 32]: A = K (m=j, 2 tiles), B = Q. 8 MFMAs of 32x32x16.
    floatx16 st[2];
#pragma unroll
    for (int m = 0; m < 2; ++m)
#pragma unroll
      for (int r = 0; r < 16; ++r) st[m][r] = 0.f;
    __builtin_amdgcn_s_setprio(1);
#pragma unroll
    for (int kf = 0; kf < 4; ++kf)
#pragma unroll
      for (int m = 0; m < 2; ++m) {
        int row = m * 32 + l31;  // j
        half8 kb = *(const half8*)(kl + row * 64 + ((kf * 2 + hw) ^ (row & 7)) * 8);
        st[m] = __builtin_amdgcn_mfma_f32_32x32x16_f16(kb, qf[kf], st[m], 0, 0, 0);
      }
    __builtin_amdgcn_s_setprio(0);

    // exp2 -> psum + natural-k PV A-frags (cvt_pkrtz + permlane32_swap)
    half8 pa[4];
#pragma unroll
    for (int ks = 0; ks < 4; ++ks) {
      const int m = ks >> 1, rb = (ks & 1) * 8;
      float p0 = fexp2(st[m][rb + 0]);
      float p1 = fexp2(st[m][rb + 1]);
      float p2 = fexp2(st[m][rb + 2]);
      float p3 = fexp2(st[m][rb + 3]);
      float p4 = fexp2(st[m][rb + 4]);
      float p5 = fexp2(st[m][rb + 5]);
      float p6 = fexp2(st[m][rb + 6]);
      float p7 = fexp2(st[m][rb + 7]);
      psum += ((p0 + p1) + (p2 + p3)) + ((p4 + p5) + (p6 + p7));
      unsigned uA = cvtpk_u32(p0, p1);
      unsigned uB = cvtpk_u32(p2, p3);
      unsigned uC = cvtpk_u32(p4, p5);
      unsigned uD = cvtpk_u32(p6, p7);
#if __has_builtin(__builtin_amdgcn_permlane32_swap)
      uint2v sAC = __builtin_bit_cast(uint2v, __builtin_amdgcn_permlane32_swap(uA, uC, false, false));
      uint2v sBD = __builtin_bit_cast(uint2v, __builtin_amdgcn_permlane32_swap(uB, uD, false, false));
      uint4v u;
      u.x = sAC.x; u.y = sBD.x; u.z = sAC.y; u.w = sBD.y;
#else
      unsigned xA = (unsigned)__shfl_xor((int)uA, 32, 64);
      unsigned xB = (unsigned)__shfl_xor((int)uB, 32, 64);
      unsigned xC = (unsigned)__shfl_xor((int)uC, 32, 64);
      unsigned xD = (unsigned)__shfl_xor((int)uD, 32, 64);
      uint4v u;
      u.x = hw ? xC : uA;
      u.y = hw ? xD : uB;
      u.z = hw ? uC : xA;
      u.w = hw ? uD : xB;
#endif
      pa[ks] = __builtin_bit_cast(half8, u);
    }

    // O[q 32][d 64] += P@V. 8 MFMAs; V B-frag natural b128:
    // lane l31 = d-col (vT row), k = j = ks*16 + hw*8 + i -> chunk ks*2+hw.
    __builtin_amdgcn_s_setprio(1);
#pragma unroll
    for (int ks = 0; ks < 4; ++ks)
#pragma unroll
      for (int dt = 0; dt < 2; ++dt) {
        int row = dt * 32 + l31;  // d
        half8 vb = *(const half8*)(vl + row * 64 + ((ks * 2 + hw) ^ (row & 7)) * 8);
        o[dt] = __builtin_amdgcn_mfma_f32_32x32x16_f16(pa[ks], vb, o[dt], 0, 0, 0);
      }
    __builtin_amdgcn_s_setprio(0);
    cur ^= 1;
  }

  // psum: lane holds sum over its half's j for q = q0w + l31
  psum += __shfl_xor(psum, 32, 64);
  if (hw == 0) psums[((size_t)(js * 32 + bh)) * SEQ + q0w + l31] = psum;

  // unnormalized O -> fp16 partials; q = q0w + (r&3)+8(r>>2)+4hw, d = dt*32+l31
#pragma unroll
  for (int dt = 0; dt < 2; ++dt)
#pragma unroll
    for (int r = 0; r < 16; ++r) {
      int n = q0w + (r & 3) + 8 * (r >> 2) + 4 * hw;
      opart[((size_t)(js * 32 + bh) * SEQ + n) * DH + dt * 32 + l31] = (half_t)o[dt][r];
    }
}

extern "C" void kernel_launch(void* const* d_in, const int* in_sizes, int n_in,
                              void* d_out, int out_size, void* d_ws, size_t ws_size,
                              hipStream_t stream) {
  const float* x = (const float*)d_in[0];
  const float* w_qkv = (const float*)d_in[1];
  const float* w_proj = (const float*)d_in[2];
  const float* head_w = (const float*)d_in[3];
  float* out = (float*)d_out;

  half_t* x16 = (half_t*)d_ws;                          // 4096*1024
  half_t* wq16 = x16 + (size_t)ROWS * DIM_;             // 3072*1024
  half_t* wp16 = wq16 + (size_t)3 * DIM_ * DIM_;        // 1024*1024
  half_t* q16 = wp16 + (size_t)DIM_ * DIM_;             // [B,H,N,Dh] (scaled by 0.125*log2e)
  half_t* k16 = q16 + (size_t)ROWS * DIM_;              // [B,H,N,Dh]
  half_t* vT16 = k16 + (size_t)ROWS * DIM_;             // [B,H,Dh,N]
  half_t* opart = vT16 + (size_t)ROWS * DIM_;           // [NJS][32][2048][64] fp16
  float* psums = (float*)(opart + (size_t)NJS * 32 * SEQ * DH);  // [NJS][32][2048] f32

  const int nx = ROWS * DIM_ / 4, nq = 3 * DIM_ * DIM_ / 4, np = DIM_ * DIM_ / 4;
  convert_all<<<(nx + nq + np) / 256, 256, 0, stream>>>((const float4*)x, (const float4*)w_qkv,
                                                        (const float4*)w_proj, (half4_t*)x16,
                                                        nx, nq, np);

  gemm32<0, 128><<<dim3(24, 32), 256, 0, stream>>>(x16, wq16, q16, k16, vT16, nullptr,
                                                   nullptr, nullptr, nullptr);
  attn_p1<<<32 * 16 * NJS, 256, 0, stream>>>(q16, k16, vT16, opart, psums);
  // proj GEMM with combine fused into A-staging (reads opart/psums directly)
  gemm32<2, 64><<<dim3(16, 32), 256, 0, stream>>>(nullptr, wp16, nullptr, nullptr, nullptr, out,
                                                  opart, psums, head_w);
}

// Round 9
// 183.726 us; speedup vs baseline: 1.1560x; 1.0338x over previous
//
#include <hip/hip_runtime.h>

typedef _Float16 half_t;
typedef _Float16 half8 __attribute__((ext_vector_type(8)));
typedef _Float16 half4_t __attribute__((ext_vector_type(4)));
typedef _Float16 half2_t __attribute__((ext_vector_type(2)));
typedef float floatx4 __attribute__((ext_vector_type(4)));
typedef float floatx16 __attribute__((ext_vector_type(16)));
typedef unsigned int uint4v __attribute__((ext_vector_type(4)));
typedef unsigned int uint2v __attribute__((ext_vector_type(2)));

#define B_SZ 2
#define SEQ 2048
#define DIM_ 1024
#define NH 16
#define DH 64
#define ROWS (B_SZ * SEQ)   // 4096
#define NJS 2               // j-split ways; attn grid 32*8*NJS = 512 blocks

// async global->LDS, 16B per lane; LDS dest = wave-uniform base + lane*16
__device__ __forceinline__ void gl2lds16(const void* g, void* l) {
  __builtin_amdgcn_global_load_lds((const __attribute__((address_space(1))) unsigned int*)g,
                                   (__attribute__((address_space(3))) unsigned int*)l, 16, 0, 0);
}

// exp2 (single v_exp_f32; log2(e) folded into q scale at GEMM epilogue)
__device__ __forceinline__ float fexp2(float x) {
#if __has_builtin(__builtin_amdgcn_exp2f)
  return __builtin_amdgcn_exp2f(x);
#else
  return __expf(x * 0.6931471805599453f);
#endif
}

__device__ __forceinline__ unsigned cvtpk_u32(float a, float b) {
#if __has_builtin(__builtin_amdgcn_cvt_pkrtz)
  return __builtin_bit_cast(unsigned, __builtin_amdgcn_cvt_pkrtz(a, b));
#else
  half2_t h; h.x = (half_t)a; h.y = (half_t)b;
  return __builtin_bit_cast(unsigned, h);
#endif
}

// one kernel converts x, w_qkv, w_proj (contiguous in ws) fp32->fp16
__global__ __launch_bounds__(256) void convert_all(const float4* __restrict__ x,
                                                   const float4* __restrict__ wq,
                                                   const float4* __restrict__ wp,
                                                   half4_t* __restrict__ dst,
                                                   int nx, int nq, int np) {
  int i = blockIdx.x * blockDim.x + threadIdx.x;
  float4 v;
  if (i < nx) v = x[i];
  else if (i < nx + nq) v = wq[i - nx];
  else if (i < nx + nq + np) v = wp[i - nx - nq];
  else return;
  half4_t h;
  h.x = (half_t)v.x; h.y = (half_t)v.y; h.z = (half_t)v.z; h.w = (half_t)v.w;
  dst[i] = h;
}

// C = A[4096][1024] @ Bt[N][1024]^T. 32x32x16 MFMA, BK=64, 128xBN tile, 4 waves.
// MODE 0 (BN=128): qkv epilogue. MODE 1 (BN=64): proj fp32 out.  (R6 config.)
template <int MODE, int BN>
__global__ __launch_bounds__(256) void gemm32(const half_t* __restrict__ A,
                                              const half_t* __restrict__ Bt,
                                              half_t* __restrict__ q16,
                                              half_t* __restrict__ k16,
                                              half_t* __restrict__ vT16,
                                              float* __restrict__ outp) {
  constexpr int K = 1024;
  constexpr int NT = BN / 64;  // 32x32 n-tiles per wave
  __shared__ __align__(16) half_t a_lds[128 * 64];
  __shared__ __align__(16) half_t b_lds[BN * 64];
  const int t = threadIdx.x;
  const int wave = t >> 6, lane = t & 63;
  const int l31 = lane & 31, hw = lane >> 5;
  const int wm = wave >> 1, wn = wave & 1;
  const int row0 = blockIdx.y * 128, col0 = blockIdx.x * BN;

  floatx16 acc[2][NT];
#pragma unroll
  for (int i = 0; i < 2; ++i)
#pragma unroll
    for (int j = 0; j < NT; ++j)
#pragma unroll
      for (int r = 0; r < 16; ++r) acc[i][j][r] = 0.f;

  for (int k0 = 0; k0 < K; k0 += 64) {
    // A: 128 rows x 8 chunks(16B) = 1024 segs, 4/thread
#pragma unroll
    for (int hi = 0; hi < 4; ++hi) {
      int s = t + hi * 256;
      int row = s >> 3, c = s & 7;
      int sc = c ^ (row & 7);
      gl2lds16(A + (size_t)(row0 + row) * K + (k0 + sc * 8), a_lds + (wave * 64 + hi * 256) * 8);
    }
    // B: BN rows x 8 chunks
#pragma unroll
    for (int hi = 0; hi < BN / 32; ++hi) {
      int s = t + hi * 256;
      int row = s >> 3, c = s & 7;
      int sc = c ^ (row & 7);
      gl2lds16(Bt + (size_t)(col0 + row) * K + (k0 + sc * 8), b_lds + (wave * 64 + hi * 256) * 8);
    }
    __syncthreads();
    half8 af[2][4], bf[NT][4];
#pragma unroll
    for (int mt = 0; mt < 2; ++mt) {
      int row = wm * 64 + mt * 32 + l31;
#pragma unroll
      for (int kf = 0; kf < 4; ++kf)
        af[mt][kf] = *(const half8*)(a_lds + row * 64 + ((kf * 2 + hw) ^ (row & 7)) * 8);
    }
#pragma unroll
    for (int nt = 0; nt < NT; ++nt) {
      int row = wn * (BN / 2) + nt * 32 + l31;
#pragma unroll
      for (int kf = 0; kf < 4; ++kf)
        bf[nt][kf] = *(const half8*)(b_lds + row * 64 + ((kf * 2 + hw) ^ (row & 7)) * 8);
    }
#pragma unroll
    for (int kf = 0; kf < 4; ++kf)
#pragma unroll
      for (int mt = 0; mt < 2; ++mt)
#pragma unroll
        for (int nt = 0; nt < NT; ++nt)
          acc[mt][nt] =
              __builtin_amdgcn_mfma_f32_32x32x16_f16(af[mt][kf], bf[nt][kf], acc[mt][nt], 0, 0, 0);
    __syncthreads();
  }

  // C/D 32x32 mapping: col = lane&31, row = (r&3) + 8*(r>>2) + 4*(lane>>5)
  if (MODE == 0) {
    const int which = col0 >> 10;
#pragma unroll
    for (int mt = 0; mt < 2; ++mt)
#pragma unroll
      for (int nt = 0; nt < NT; ++nt) {
        int growb = row0 + wm * 64 + mt * 32;
        int gcol = col0 + wn * (BN / 2) + nt * 32 + l31;
        int hc = gcol & 1023, h = hc >> 6, d = hc & 63;
        if (which == 2) {
#pragma unroll
          for (int rq = 0; rq < 4; ++rq) {
            int grow = growb + 8 * rq + 4 * hw;
            int b = grow >> 11, n0 = grow & 2047;
            int bh = b * NH + h;
            half4_t h4;
            h4.x = (half_t)acc[mt][nt][rq * 4 + 0];
            h4.y = (half_t)acc[mt][nt][rq * 4 + 1];
            h4.z = (half_t)acc[mt][nt][rq * 4 + 2];
            h4.w = (half_t)acc[mt][nt][rq * 4 + 3];
            *(half4_t*)(vT16 + ((size_t)bh * DH + d) * SEQ + n0) = h4;
          }
        } else {
#pragma unroll
          for (int r = 0; r < 16; ++r) {
            int grow = growb + (r & 3) + 8 * (r >> 2) + 4 * hw;
            int b = grow >> 11, n = grow & 2047;
            int bh = b * NH + h;
            float v = acc[mt][nt][r];
            if (which == 0)
              q16[((size_t)bh * SEQ + n) * DH + d] =
                  (half_t)(v * 0.1803368801111204f);  // fold SCALE * log2(e)
            else
              k16[((size_t)bh * SEQ + n) * DH + d] = (half_t)v;
          }
        }
      }
  } else {
#pragma unroll
    for (int mt = 0; mt < 2; ++mt)
#pragma unroll
      for (int nt = 0; nt < NT; ++nt) {
        int growb = row0 + wm * 64 + mt * 32;
        int gcol = col0 + wn * (BN / 2) + nt * 32 + l31;
#pragma unroll
        for (int r = 0; r < 16; ++r) {
          int grow = growb + (r & 3) + 8 * (r >> 2) + 4 * hw;
          outp[(size_t)grow * DIM_ + gcol] = acc[mt][nt][r];
        }
      }
  }
}

// Flash attention pass 1, all-32x32x16. Block = 8 waves x 32 q = 256 q-rows;
// j-slice SEQ/NJS. 512 blocks @512 threads = 2 blocks/CU x 8 waves = 4
// waves/SIMD; each K/V 64-tile staged once serves 256 q-rows (staging
// traffic halved vs 4-wave blocks). Inner loop identical to R4/R6 config:
// S^T = mfma(K,Q), lane l31 = q; PV A-frags natural-k via cvt_pkrtz +
// permlane32_swap; V B-frags natural b128.
__global__ __launch_bounds__(512, 4) void attn_p1(const half_t* __restrict__ q16,
                                                  const half_t* __restrict__ k16,
                                                  const half_t* __restrict__ vT16,
                                                  half_t* __restrict__ opart,
                                                  float* __restrict__ psums) {
  __shared__ __align__(16) half_t k_lds[2][64 * 64];  // [j][d]
  __shared__ __align__(16) half_t v_lds[2][64 * 64];  // vT: [d][j]

  const int t = threadIdx.x;
  const int wave = t >> 6, lane = t & 63;
  const int l31 = lane & 31, hw = lane >> 5;
  const int blk = blockIdx.x;
  const int js = blk & (NJS - 1), qt = (blk / NJS) & 7, bh = blk / (NJS * 8);
  const half_t* qp = q16 + (size_t)bh * SEQ * DH;
  const half_t* kp = k16 + (size_t)bh * SEQ * DH;
  const half_t* vp = vT16 + (size_t)bh * DH * SEQ;
  const int q0w = qt * 256 + wave * 32;
  const int jbase = js * (SEQ / NJS);
  constexpr int NJT = (SEQ / NJS) / 64;  // 16

  // staging: 512 segs of 16B (64 rows x 8 chunks), 1 seg/thread, chunk XOR row&7
  const int r0_ = t >> 3, c0_ = (t & 7) ^ (r0_ & 7);

  // Q fragments, B-operand 32x32x16: col = l31 = q, k = kf*16 + hw*8 + i
  half8 qf[4];
#pragma unroll
  for (int kf = 0; kf < 4; ++kf)
    qf[kf] = *(const half8*)(qp + (size_t)(q0w + l31) * DH + kf * 16 + hw * 8);

  floatx16 o[2];  // [d-tile]; C/D: col=l31=d, row=(r&3)+8(r>>2)+4hw = q
#pragma unroll
  for (int i = 0; i < 2; ++i)
#pragma unroll
    for (int r = 0; r < 16; ++r) o[i][r] = 0.f;
  float psum = 0.f;

  // prologue: stage tile jbase into buffer 0 (1 K-seg + 1 V-seg per thread)
  gl2lds16(kp + (size_t)(jbase + r0_) * DH + c0_ * 8, &k_lds[0][(wave * 64) * 8]);
  gl2lds16(vp + (size_t)r0_ * SEQ + jbase + c0_ * 8, &v_lds[0][(wave * 64) * 8]);

  int cur = 0;
  for (int jt = 0; jt < NJT; ++jt) {
    __syncthreads();  // publishes buf[cur], protects buf[cur^1]

    if (jt + 1 < NJT) {
      const int j0 = jbase + (jt + 1) * 64, nb = cur ^ 1;
      gl2lds16(kp + (size_t)(j0 + r0_) * DH + c0_ * 8, &k_lds[nb][(wave * 64) * 8]);
      gl2lds16(vp + (size_t)r0_ * SEQ + j0 + c0_ * 8, &v_lds[nb][(wave * 64) * 8]);
    }

    const half_t* kl = k_lds[cur];
    const half_t* vl = v_lds[cur];

    // S^T[j 64][q 32]: A = K (m=j, 2 tiles), B = Q. 8 MFMAs of 32x32x16.
    floatx16 st[2];
#pragma unroll
    for (int m = 0; m < 2; ++m)
#pragma unroll
      for (int r = 0; r < 16; ++r) st[m][r] = 0.f;
    __builtin_amdgcn_s_setprio(1);
#pragma unroll
    for (int kf = 0; kf < 4; ++kf)
#pragma unroll
      for (int m = 0; m < 2; ++m) {
        int row = m * 32 + l31;  // j
        half8 kb = *(const half8*)(kl + row * 64 + ((kf * 2 + hw) ^ (row & 7)) * 8);
        st[m] = __builtin_amdgcn_mfma_f32_32x32x16_f16(kb, qf[kf], st[m], 0, 0, 0);
      }
    __builtin_amdgcn_s_setprio(0);

    // exp2 -> psum + natural-k PV A-frags (cvt_pkrtz + permlane32_swap)
    half8 pa[4];
#pragma unroll
    for (int ks = 0; ks < 4; ++ks) {
      const int m = ks >> 1, rb = (ks & 1) * 8;
      float p0 = fexp2(st[m][rb + 0]);
      float p1 = fexp2(st[m][rb + 1]);
      float p2 = fexp2(st[m][rb + 2]);
      float p3 = fexp2(st[m][rb + 3]);
      float p4 = fexp2(st[m][rb + 4]);
      float p5 = fexp2(st[m][rb + 5]);
      float p6 = fexp2(st[m][rb + 6]);
      float p7 = fexp2(st[m][rb + 7]);
      psum += ((p0 + p1) + (p2 + p3)) + ((p4 + p5) + (p6 + p7));
      unsigned uA = cvtpk_u32(p0, p1);
      unsigned uB = cvtpk_u32(p2, p3);
      unsigned uC = cvtpk_u32(p4, p5);
      unsigned uD = cvtpk_u32(p6, p7);
#if __has_builtin(__builtin_amdgcn_permlane32_swap)
      uint2v sAC = __builtin_bit_cast(uint2v, __builtin_amdgcn_permlane32_swap(uA, uC, false, false));
      uint2v sBD = __builtin_bit_cast(uint2v, __builtin_amdgcn_permlane32_swap(uB, uD, false, false));
      uint4v u;
      u.x = sAC.x; u.y = sBD.x; u.z = sAC.y; u.w = sBD.y;
#else
      unsigned xA = (unsigned)__shfl_xor((int)uA, 32, 64);
      unsigned xB = (unsigned)__shfl_xor((int)uB, 32, 64);
      unsigned xC = (unsigned)__shfl_xor((int)uC, 32, 64);
      unsigned xD = (unsigned)__shfl_xor((int)uD, 32, 64);
      uint4v u;
      u.x = hw ? xC : uA;
      u.y = hw ? xD : uB;
      u.z = hw ? uC : xA;
      u.w = hw ? uD : xB;
#endif
      pa[ks] = __builtin_bit_cast(half8, u);
    }

    // O[q 32][d 64] += P@V. 8 MFMAs; V B-frag natural b128:
    // lane l31 = d-col (vT row), k = j = ks*16 + hw*8 + i -> chunk ks*2+hw.
    __builtin_amdgcn_s_setprio(1);
#pragma unroll
    for (int ks = 0; ks < 4; ++ks)
#pragma unroll
      for (int dt = 0; dt < 2; ++dt) {
        int row = dt * 32 + l31;  // d
        half8 vb = *(const half8*)(vl + row * 64 + ((ks * 2 + hw) ^ (row & 7)) * 8);
        o[dt] = __builtin_amdgcn_mfma_f32_32x32x16_f16(pa[ks], vb, o[dt], 0, 0, 0);
      }
    __builtin_amdgcn_s_setprio(0);
    cur ^= 1;
  }

  // psum: lane holds sum over its half's j for q = q0w + l31
  psum += __shfl_xor(psum, 32, 64);
  if (hw == 0) psums[((size_t)(js * 32 + bh)) * SEQ + q0w + l31] = psum;

  // unnormalized O -> fp16 partials; q = q0w + (r&3)+8(r>>2)+4hw, d = dt*32+l31
#pragma unroll
  for (int dt = 0; dt < 2; ++dt)
#pragma unroll
    for (int r = 0; r < 16; ++r) {
      int n = q0w + (r & 3) + 8 * (r >> 2) + 4 * hw;
      opart[((size_t)(js * 32 + bh) * SEQ + n) * DH + dt * 32 + l31] = (half_t)o[dt][r];
    }
}

// combine: out = (sum_js O_js) * softmax(head_w)[h] / (sum_js ps_js), fp16 attn16
__global__ __launch_bounds__(256) void combine(const half_t* __restrict__ opart,
                                               const float* __restrict__ psums,
                                               const float* __restrict__ head_w,
                                               half_t* __restrict__ attn16) {
  int idx = blockIdx.x * blockDim.x + threadIdx.x;  // 1M threads, 4 d each
  int d4 = idx & 15, n = (idx >> 4) & 2047, bh = idx >> 15;
  int h = bh & 15, b = bh >> 4;
  const size_t jstr = (size_t)32 * SEQ * DH;
  size_t off = ((size_t)bh * SEQ + n) * DH + d4 * 4;

  float sx = 0.f, sy = 0.f, sz = 0.f, sw2 = 0.f, ps = 0.f;
#pragma unroll
  for (int js = 0; js < NJS; ++js) {
    half4_t ov = *(const half4_t*)(opart + js * jstr + off);
    sx += (float)ov.x; sy += (float)ov.y; sz += (float)ov.z; sw2 += (float)ov.w;
    ps += psums[(size_t)js * 32 * SEQ + (size_t)bh * SEQ + n];
  }

  float mw = head_w[0];
#pragma unroll
  for (int i = 1; i < NH; ++i) mw = fmaxf(mw, head_w[i]);
  float sw = 0.f;
#pragma unroll
  for (int i = 0; i < NH; ++i) sw += __expf(head_w[i] - mw);
  float hwv = __expf(head_w[h] - mw) / sw;

  float scl = hwv / ps;
  half4_t r;
  r.x = (half_t)(sx * scl);
  r.y = (half_t)(sy * scl);
  r.z = (half_t)(sz * scl);
  r.w = (half_t)(sw2 * scl);
  *(half4_t*)(attn16 + ((size_t)(b * SEQ + n)) * DIM_ + h * DH + d4 * 4) = r;
}

extern "C" void kernel_launch(void* const* d_in, const int* in_sizes, int n_in,
                              void* d_out, int out_size, void* d_ws, size_t ws_size,
                              hipStream_t stream) {
  const float* x = (const float*)d_in[0];
  const float* w_qkv = (const float*)d_in[1];
  const float* w_proj = (const float*)d_in[2];
  const float* head_w = (const float*)d_in[3];
  float* out = (float*)d_out;

  half_t* x16 = (half_t*)d_ws;                          // 4096*1024
  half_t* wq16 = x16 + (size_t)ROWS * DIM_;             // 3072*1024
  half_t* wp16 = wq16 + (size_t)3 * DIM_ * DIM_;        // 1024*1024
  half_t* q16 = wp16 + (size_t)DIM_ * DIM_;             // [B,H,N,Dh] (scaled by 0.125*log2e)
  half_t* k16 = q16 + (size_t)ROWS * DIM_;              // [B,H,N,Dh]
  half_t* vT16 = k16 + (size_t)ROWS * DIM_;             // [B,H,Dh,N]
  half_t* attn16 = vT16 + (size_t)ROWS * DIM_;          // [B*N, DIM]
  half_t* opart = attn16 + (size_t)ROWS * DIM_;         // [NJS][32][2048][64] fp16
  float* psums = (float*)(opart + (size_t)NJS * 32 * SEQ * DH);  // [NJS][32][2048] f32

  const int nx = ROWS * DIM_ / 4, nq = 3 * DIM_ * DIM_ / 4, np = DIM_ * DIM_ / 4;
  convert_all<<<(nx + nq + np) / 256, 256, 0, stream>>>((const float4*)x, (const float4*)w_qkv,
                                                        (const float4*)w_proj, (half4_t*)x16,
                                                        nx, nq, np);

  gemm32<0, 128><<<dim3(24, 32), 256, 0, stream>>>(x16, wq16, q16, k16, vT16, nullptr);
  attn_p1<<<32 * 8 * NJS, 512, 0, stream>>>(q16, k16, vT16, opart, psums);
  combine<<<(32 * SEQ * DH / 4) / 256, 256, 0, stream>>>(opart, psums, head_w, attn16);
  gemm32<1, 64><<<dim3(16, 32), 256, 0, stream>>>(attn16, wp16, nullptr, nullptr, nullptr, out);
}

// Round 10
// 183.198 us; speedup vs baseline: 1.1593x; 1.0029x over previous
//
#include <hip/hip_runtime.h>

typedef _Float16 half_t;
typedef _Float16 half8 __attribute__((ext_vector_type(8)));
typedef _Float16 half4_t __attribute__((ext_vector_type(4)));
typedef _Float16 half2_t __attribute__((ext_vector_type(2)));
typedef float floatx4 __attribute__((ext_vector_type(4)));
typedef float floatx16 __attribute__((ext_vector_type(16)));
typedef unsigned int uint4v __attribute__((ext_vector_type(4)));
typedef unsigned int uint2v __attribute__((ext_vector_type(2)));

#define B_SZ 2
#define SEQ 2048
#define DIM_ 1024
#define NH 16
#define DH 64
#define ROWS (B_SZ * SEQ)   // 4096
#define NJS 2               // j-split ways; attn grid 32*8*NJS = 512 blocks

// async global->LDS, 16B per lane; LDS dest = wave-uniform base + lane*16
__device__ __forceinline__ void gl2lds16(const void* g, void* l) {
  __builtin_amdgcn_global_load_lds((const __attribute__((address_space(1))) unsigned int*)g,
                                   (__attribute__((address_space(3))) unsigned int*)l, 16, 0, 0);
}

// exp2 (single v_exp_f32; log2(e) folded into q scale at GEMM epilogue)
__device__ __forceinline__ float fexp2(float x) {
#if __has_builtin(__builtin_amdgcn_exp2f)
  return __builtin_amdgcn_exp2f(x);
#else
  return __expf(x * 0.6931471805599453f);
#endif
}

__device__ __forceinline__ unsigned cvtpk_u32(float a, float b) {
#if __has_builtin(__builtin_amdgcn_cvt_pkrtz)
  return __builtin_bit_cast(unsigned, __builtin_amdgcn_cvt_pkrtz(a, b));
#else
  half2_t h; h.x = (half_t)a; h.y = (half_t)b;
  return __builtin_bit_cast(unsigned, h);
#endif
}

// one kernel converts x, w_qkv, w_proj (contiguous in ws) fp32->fp16
__global__ __launch_bounds__(256) void convert_all(const float4* __restrict__ x,
                                                   const float4* __restrict__ wq,
                                                   const float4* __restrict__ wp,
                                                   half4_t* __restrict__ dst,
                                                   int nx, int nq, int np) {
  int i = blockIdx.x * blockDim.x + threadIdx.x;
  float4 v;
  if (i < nx) v = x[i];
  else if (i < nx + nq) v = wq[i - nx];
  else if (i < nx + nq + np) v = wp[i - nx - nq];
  else return;
  half4_t h;
  h.x = (half_t)v.x; h.y = (half_t)v.y; h.z = (half_t)v.z; h.w = (half_t)v.w;
  dst[i] = h;
}

// C = A[4096][1024] @ Bt[N][1024]^T. 32x32x16 MFMA, BK=64, 128xBN tile, 4 waves.
// MODE 0 (BN=128): qkv epilogue. MODE 1 (BN=64): proj fp32 out.
// XCD-aware bijective block swizzle (grids 768/512, both % 8 == 0): chunks of
// grid/8 consecutive tiles share one XCD's L2 (proj: whole B = 2MB fits).
template <int MODE, int BN>
__global__ __launch_bounds__(256) void gemm32(const half_t* __restrict__ A,
                                              const half_t* __restrict__ Bt,
                                              half_t* __restrict__ q16,
                                              half_t* __restrict__ k16,
                                              half_t* __restrict__ vT16,
                                              float* __restrict__ outp) {
  constexpr int K = 1024;
  constexpr int NT = BN / 64;  // 32x32 n-tiles per wave
  __shared__ __align__(16) half_t a_lds[128 * 64];
  __shared__ __align__(16) half_t b_lds[BN * 64];
  const int t = threadIdx.x;
  const int wave = t >> 6, lane = t & 63;
  const int l31 = lane & 31, hw = lane >> 5;
  const int wm = wave >> 1, wn = wave & 1;

  // XCD swizzle
  const int lin = blockIdx.y * gridDim.x + blockIdx.x;
  const int cpx = (gridDim.x * gridDim.y) >> 3;
  const int nl = (lin & 7) * cpx + (lin >> 3);
  const int bx = nl % gridDim.x, by = nl / gridDim.x;
  const int row0 = by * 128, col0 = bx * BN;

  floatx16 acc[2][NT];
#pragma unroll
  for (int i = 0; i < 2; ++i)
#pragma unroll
    for (int j = 0; j < NT; ++j)
#pragma unroll
      for (int r = 0; r < 16; ++r) acc[i][j][r] = 0.f;

  for (int k0 = 0; k0 < K; k0 += 64) {
    // A: 128 rows x 8 chunks(16B) = 1024 segs, 4/thread
#pragma unroll
    for (int hi = 0; hi < 4; ++hi) {
      int s = t + hi * 256;
      int row = s >> 3, c = s & 7;
      int sc = c ^ (row & 7);
      gl2lds16(A + (size_t)(row0 + row) * K + (k0 + sc * 8), a_lds + (wave * 64 + hi * 256) * 8);
    }
    // B: BN rows x 8 chunks
#pragma unroll
    for (int hi = 0; hi < BN / 32; ++hi) {
      int s = t + hi * 256;
      int row = s >> 3, c = s & 7;
      int sc = c ^ (row & 7);
      gl2lds16(Bt + (size_t)(col0 + row) * K + (k0 + sc * 8), b_lds + (wave * 64 + hi * 256) * 8);
    }
    __syncthreads();
    half8 af[2][4], bf[NT][4];
#pragma unroll
    for (int mt = 0; mt < 2; ++mt) {
      int row = wm * 64 + mt * 32 + l31;
#pragma unroll
      for (int kf = 0; kf < 4; ++kf)
        af[mt][kf] = *(const half8*)(a_lds + row * 64 + ((kf * 2 + hw) ^ (row & 7)) * 8);
    }
#pragma unroll
    for (int nt = 0; nt < NT; ++nt) {
      int row = wn * (BN / 2) + nt * 32 + l31;
#pragma unroll
      for (int kf = 0; kf < 4; ++kf)
        bf[nt][kf] = *(const half8*)(b_lds + row * 64 + ((kf * 2 + hw) ^ (row & 7)) * 8);
    }
#pragma unroll
    for (int kf = 0; kf < 4; ++kf)
#pragma unroll
      for (int mt = 0; mt < 2; ++mt)
#pragma unroll
        for (int nt = 0; nt < NT; ++nt)
          acc[mt][nt] =
              __builtin_amdgcn_mfma_f32_32x32x16_f16(af[mt][kf], bf[nt][kf], acc[mt][nt], 0, 0, 0);
    __syncthreads();
  }

  // C/D 32x32 mapping: col = lane&31, row = (r&3) + 8*(r>>2) + 4*(lane>>5)
  if (MODE == 0) {
    const int which = col0 >> 10;
#pragma unroll
    for (int mt = 0; mt < 2; ++mt)
#pragma unroll
      for (int nt = 0; nt < NT; ++nt) {
        int growb = row0 + wm * 64 + mt * 32;
        int gcol = col0 + wn * (BN / 2) + nt * 32 + l31;
        int hc = gcol & 1023, h = hc >> 6, d = hc & 63;
        if (which == 2) {
#pragma unroll
          for (int rq = 0; rq < 4; ++rq) {
            int grow = growb + 8 * rq + 4 * hw;
            int b = grow >> 11, n0 = grow & 2047;
            int bh = b * NH + h;
            half4_t h4;
            h4.x = (half_t)acc[mt][nt][rq * 4 + 0];
            h4.y = (half_t)acc[mt][nt][rq * 4 + 1];
            h4.z = (half_t)acc[mt][nt][rq * 4 + 2];
            h4.w = (half_t)acc[mt][nt][rq * 4 + 3];
            *(half4_t*)(vT16 + ((size_t)bh * DH + d) * SEQ + n0) = h4;
          }
        } else {
#pragma unroll
          for (int r = 0; r < 16; ++r) {
            int grow = growb + (r & 3) + 8 * (r >> 2) + 4 * hw;
            int b = grow >> 11, n = grow & 2047;
            int bh = b * NH + h;
            float v = acc[mt][nt][r];
            if (which == 0)
              q16[((size_t)bh * SEQ + n) * DH + d] =
                  (half_t)(v * 0.1803368801111204f);  // fold SCALE * log2(e)
            else
              k16[((size_t)bh * SEQ + n) * DH + d] = (half_t)v;
          }
        }
      }
  } else {
#pragma unroll
    for (int mt = 0; mt < 2; ++mt)
#pragma unroll
      for (int nt = 0; nt < NT; ++nt) {
        int growb = row0 + wm * 64 + mt * 32;
        int gcol = col0 + wn * (BN / 2) + nt * 32 + l31;
#pragma unroll
        for (int r = 0; r < 16; ++r) {
          int grow = growb + (r & 3) + 8 * (r >> 2) + 4 * hw;
          outp[(size_t)grow * DIM_ + gcol] = acc[mt][nt][r];
        }
      }
  }
}

// Flash attention pass 1, all-32x32x16. Block = 4 waves x 64 q = 256 q-rows;
// each wave owns TWO 32-q tiles (qi=0,1): K/V b128 reads are q-independent so
// each LDS read now feeds 2 MFMAs -> LDS-read + conflict cycles per FLOP
// halve (the dominant pipe). m-major QK->exp ordering frees st early to keep
// VGPR peak ~190 (launch_bounds(256,2)). Grid 32*8*NJS = 512 = 2 blocks/CU.
__global__ __launch_bounds__(256, 2) void attn_p1(const half_t* __restrict__ q16,
                                                  const half_t* __restrict__ k16,
                                                  const half_t* __restrict__ vT16,
                                                  half_t* __restrict__ opart,
                                                  float* __restrict__ psums) {
  __shared__ __align__(16) half_t k_lds[2][64 * 64];  // [j][d]
  __shared__ __align__(16) half_t v_lds[2][64 * 64];  // vT: [d][j]

  const int t = threadIdx.x;
  const int wave = t >> 6, lane = t & 63;
  const int l31 = lane & 31, hw = lane >> 5;
  const int blk = blockIdx.x;
  const int js = blk & (NJS - 1), qt = (blk / NJS) & 7, bh = blk / (NJS * 8);
  const half_t* qp = q16 + (size_t)bh * SEQ * DH;
  const half_t* kp = k16 + (size_t)bh * SEQ * DH;
  const half_t* vp = vT16 + (size_t)bh * DH * SEQ;
  const int q0w = qt * 256 + wave * 64;
  const int jbase = js * (SEQ / NJS);
  constexpr int NJT = (SEQ / NJS) / 64;  // 16

  // staging offsets: 512 segs of 16B (64 rows x 8 chunks), chunk XOR row&7
  const int s0 = t, s1 = t + 256;
  const int r0_ = s0 >> 3, c0_ = (s0 & 7) ^ (r0_ & 7);
  const int r1_ = s1 >> 3, c1_ = (s1 & 7) ^ (r1_ & 7);

  // Q fragments, B-operand 32x32x16: col = l31 = q, k = kf*16 + hw*8 + i
  half8 qf[2][4];
#pragma unroll
  for (int qi = 0; qi < 2; ++qi)
#pragma unroll
    for (int kf = 0; kf < 4; ++kf)
      qf[qi][kf] =
          *(const half8*)(qp + (size_t)(q0w + qi * 32 + l31) * DH + kf * 16 + hw * 8);

  floatx16 o[2][2];  // [qi][d-tile]; C/D: col=l31=d, row=(r&3)+8(r>>2)+4hw = q
#pragma unroll
  for (int qi = 0; qi < 2; ++qi)
#pragma unroll
    for (int i = 0; i < 2; ++i)
#pragma unroll
      for (int r = 0; r < 16; ++r) o[qi][i][r] = 0.f;
  float psum[2] = {0.f, 0.f};

  // prologue: stage tile jbase into buffer 0
  gl2lds16(kp + (size_t)(jbase + r0_) * DH + c0_ * 8, &k_lds[0][(wave * 64) * 8]);
  gl2lds16(vp + (size_t)r0_ * SEQ + jbase + c0_ * 8, &v_lds[0][(wave * 64) * 8]);
  gl2lds16(kp + (size_t)(jbase + r1_) * DH + c1_ * 8, &k_lds[0][(wave * 64 + 256) * 8]);
  gl2lds16(vp + (size_t)r1_ * SEQ + jbase + c1_ * 8, &v_lds[0][(wave * 64 + 256) * 8]);

  int cur = 0;
  for (int jt = 0; jt < NJT; ++jt) {
    __syncthreads();  // publishes buf[cur], protects buf[cur^1]

    if (jt + 1 < NJT) {
      const int j0 = jbase + (jt + 1) * 64, nb = cur ^ 1;
      gl2lds16(kp + (size_t)(j0 + r0_) * DH + c0_ * 8, &k_lds[nb][(wave * 64) * 8]);
      gl2lds16(vp + (size_t)r0_ * SEQ + j0 + c0_ * 8, &v_lds[nb][(wave * 64) * 8]);
      gl2lds16(kp + (size_t)(j0 + r1_) * DH + c1_ * 8, &k_lds[nb][(wave * 64 + 256) * 8]);
      gl2lds16(vp + (size_t)r1_ * SEQ + j0 + c1_ * 8, &v_lds[nb][(wave * 64 + 256) * 8]);
    }

    const half_t* kl = k_lds[cur];
    const half_t* vl = v_lds[cur];

    // QK + exp, m-major: S^T[j 32][q 64] per m-tile, then exp -> pa, freeing st.
    half8 pa[2][4];  // [qi][ks]
#pragma unroll
    for (int m = 0; m < 2; ++m) {
      floatx16 st[2];
#pragma unroll
      for (int qi = 0; qi < 2; ++qi)
#pragma unroll
        for (int r = 0; r < 16; ++r) st[qi][r] = 0.f;
      __builtin_amdgcn_s_setprio(1);
#pragma unroll
      for (int kf = 0; kf < 4; ++kf) {
        int row = m * 32 + l31;  // j
        half8 kb = *(const half8*)(kl + row * 64 + ((kf * 2 + hw) ^ (row & 7)) * 8);
#pragma unroll
        for (int qi = 0; qi < 2; ++qi)
          st[qi] = __builtin_amdgcn_mfma_f32_32x32x16_f16(kb, qf[qi][kf], st[qi], 0, 0, 0);
      }
      __builtin_amdgcn_s_setprio(0);
      // exp2 -> psum + natural-k PV A-frags (cvt_pkrtz + permlane32_swap)
#pragma unroll
      for (int qi = 0; qi < 2; ++qi)
#pragma unroll
        for (int hh = 0; hh < 2; ++hh) {
          const int rb = hh * 8;
          float p0 = fexp2(st[qi][rb + 0]);
          float p1 = fexp2(st[qi][rb + 1]);
          float p2 = fexp2(st[qi][rb + 2]);
          float p3 = fexp2(st[qi][rb + 3]);
          float p4 = fexp2(st[qi][rb + 4]);
          float p5 = fexp2(st[qi][rb + 5]);
          float p6 = fexp2(st[qi][rb + 6]);
          float p7 = fexp2(st[qi][rb + 7]);
          psum[qi] += ((p0 + p1) + (p2 + p3)) + ((p4 + p5) + (p6 + p7));
          unsigned uA = cvtpk_u32(p0, p1);
          unsigned uB = cvtpk_u32(p2, p3);
          unsigned uC = cvtpk_u32(p4, p5);
          unsigned uD = cvtpk_u32(p6, p7);
#if __has_builtin(__builtin_amdgcn_permlane32_swap)
          uint2v sAC =
              __builtin_bit_cast(uint2v, __builtin_amdgcn_permlane32_swap(uA, uC, false, false));
          uint2v sBD =
              __builtin_bit_cast(uint2v, __builtin_amdgcn_permlane32_swap(uB, uD, false, false));
          uint4v u;
          u.x = sAC.x; u.y = sBD.x; u.z = sAC.y; u.w = sBD.y;
#else
          unsigned xA = (unsigned)__shfl_xor((int)uA, 32, 64);
          unsigned xB = (unsigned)__shfl_xor((int)uB, 32, 64);
          unsigned xC = (unsigned)__shfl_xor((int)uC, 32, 64);
          unsigned xD = (unsigned)__shfl_xor((int)uD, 32, 64);
          uint4v u;
          u.x = hw ? xC : uA;
          u.y = hw ? xD : uB;
          u.z = hw ? uC : xA;
          u.w = hw ? uD : xB;
#endif
          pa[qi][m * 2 + hh] = __builtin_bit_cast(half8, u);
        }
    }

    // O[q 64][d 64] += P@V. 16 MFMAs over 8 V b128 reads (each read feeds 2).
    __builtin_amdgcn_s_setprio(1);
#pragma unroll
    for (int ks = 0; ks < 4; ++ks)
#pragma unroll
      for (int dt = 0; dt < 2; ++dt) {
        int row = dt * 32 + l31;  // d
        half8 vb = *(const half8*)(vl + row * 64 + ((ks * 2 + hw) ^ (row & 7)) * 8);
#pragma unroll
        for (int qi = 0; qi < 2; ++qi)
          o[qi][dt] = __builtin_amdgcn_mfma_f32_32x32x16_f16(pa[qi][ks], vb, o[qi][dt], 0, 0, 0);
      }
    __builtin_amdgcn_s_setprio(0);
    cur ^= 1;
  }

  // psum: lane holds sum over its half's j for q = q0w + qi*32 + l31
#pragma unroll
  for (int qi = 0; qi < 2; ++qi) {
    psum[qi] += __shfl_xor(psum[qi], 32, 64);
    if (hw == 0) psums[((size_t)(js * 32 + bh)) * SEQ + q0w + qi * 32 + l31] = psum[qi];
  }

  // unnormalized O -> fp16 partials; q = q0w+qi*32+(r&3)+8(r>>2)+4hw, d = dt*32+l31
#pragma unroll
  for (int qi = 0; qi < 2; ++qi)
#pragma unroll
    for (int dt = 0; dt < 2; ++dt)
#pragma unroll
      for (int r = 0; r < 16; ++r) {
        int n = q0w + qi * 32 + (r & 3) + 8 * (r >> 2) + 4 * hw;
        opart[((size_t)(js * 32 + bh) * SEQ + n) * DH + dt * 32 + l31] = (half_t)o[qi][dt][r];
      }
}

// combine: out = (sum_js O_js) * softmax(head_w)[h] / (sum_js ps_js), fp16 attn16
__global__ __launch_bounds__(256) void combine(const half_t* __restrict__ opart,
                                               const float* __restrict__ psums,
                                               const float* __restrict__ head_w,
                                               half_t* __restrict__ attn16) {
  int idx = blockIdx.x * blockDim.x + threadIdx.x;  // 1M threads, 4 d each
  int d4 = idx & 15, n = (idx >> 4) & 2047, bh = idx >> 15;
  int h = bh & 15, b = bh >> 4;
  const size_t jstr = (size_t)32 * SEQ * DH;
  size_t off = ((size_t)bh * SEQ + n) * DH + d4 * 4;

  float sx = 0.f, sy = 0.f, sz = 0.f, sw2 = 0.f, ps = 0.f;
#pragma unroll
  for (int js = 0; js < NJS; ++js) {
    half4_t ov = *(const half4_t*)(opart + js * jstr + off);
    sx += (float)ov.x; sy += (float)ov.y; sz += (float)ov.z; sw2 += (float)ov.w;
    ps += psums[(size_t)js * 32 * SEQ + (size_t)bh * SEQ + n];
  }

  float mw = head_w[0];
#pragma unroll
  for (int i = 1; i < NH; ++i) mw = fmaxf(mw, head_w[i]);
  float sw = 0.f;
#pragma unroll
  for (int i = 0; i < NH; ++i) sw += __expf(head_w[i] - mw);
  float hwv = __expf(head_w[h] - mw) / sw;

  float scl = hwv / ps;
  half4_t r;
  r.x = (half_t)(sx * scl);
  r.y = (half_t)(sy * scl);
  r.z = (half_t)(sz * scl);
  r.w = (half_t)(sw2 * scl);
  *(half4_t*)(attn16 + ((size_t)(b * SEQ + n)) * DIM_ + h * DH + d4 * 4) = r;
}

extern "C" void kernel_launch(void* const* d_in, const int* in_sizes, int n_in,
                              void* d_out, int out_size, void* d_ws, size_t ws_size,
                              hipStream_t stream) {
  const float* x = (const float*)d_in[0];
  const float* w_qkv = (const float*)d_in[1];
  const float* w_proj = (const float*)d_in[2];
  const float* head_w = (const float*)d_in[3];
  float* out = (float*)d_out;

  half_t* x16 = (half_t*)d_ws;                          // 4096*1024
  half_t* wq16 = x16 + (size_t)ROWS * DIM_;             // 3072*1024
  half_t* wp16 = wq16 + (size_t)3 * DIM_ * DIM_;        // 1024*1024
  half_t* q16 = wp16 + (size_t)DIM_ * DIM_;             // [B,H,N,Dh] (scaled by 0.125*log2e)
  half_t* k16 = q16 + (size_t)ROWS * DIM_;              // [B,H,N,Dh]
  half_t* vT16 = k16 + (size_t)ROWS * DIM_;             // [B,H,Dh,N]
  half_t* attn16 = vT16 + (size_t)ROWS * DIM_;          // [B*N, DIM]
  half_t* opart = attn16 + (size_t)ROWS * DIM_;         // [NJS][32][2048][64] fp16
  float* psums = (float*)(opart + (size_t)NJS * 32 * SEQ * DH);  // [NJS][32][2048] f32

  const int nx = ROWS * DIM_ / 4, nq = 3 * DIM_ * DIM_ / 4, np = DIM_ * DIM_ / 4;
  convert_all<<<(nx + nq + np) / 256, 256, 0, stream>>>((const float4*)x, (const float4*)w_qkv,
                                                        (const float4*)w_proj, (half4_t*)x16,
                                                        nx, nq, np);

  gemm32<0, 128><<<dim3(24, 32), 256, 0, stream>>>(x16, wq16, q16, k16, vT16, nullptr);
  attn_p1<<<32 * 8 * NJS, 256, 0, stream>>>(q16, k16, vT16, opart, psums);
  combine<<<(32 * SEQ * DH / 4) / 256, 256, 0, stream>>>(opart, psums, head_w, attn16);
  gemm32<1, 64><<<dim3(16, 32), 256, 0, stream>>>(attn16, wp16, nullptr, nullptr, nullptr, out);
}

// Round 11
// 181.362 us; speedup vs baseline: 1.1711x; 1.0101x over previous
//
#include <hip/hip_runtime.h>

typedef _Float16 half_t;
typedef _Float16 half8 __attribute__((ext_vector_type(8)));
typedef _Float16 half4_t __attribute__((ext_vector_type(4)));
typedef _Float16 half2_t __attribute__((ext_vector_type(2)));
typedef float floatx4 __attribute__((ext_vector_type(4)));
typedef float floatx16 __attribute__((ext_vector_type(16)));
typedef unsigned int uint4v __attribute__((ext_vector_type(4)));
typedef unsigned int uint2v __attribute__((ext_vector_type(2)));

#define B_SZ 2
#define SEQ 2048
#define DIM_ 1024
#define NH 16
#define DH 64
#define ROWS (B_SZ * SEQ)   // 4096

// async global->LDS, 16B per lane; LDS dest = wave-uniform base + lane*16
__device__ __forceinline__ void gl2lds16(const void* g, void* l) {
  __builtin_amdgcn_global_load_lds((const __attribute__((address_space(1))) unsigned int*)g,
                                   (__attribute__((address_space(3))) unsigned int*)l, 16, 0, 0);
}

// exp2 (single v_exp_f32; log2(e) folded into q scale at GEMM epilogue)
__device__ __forceinline__ float fexp2(float x) {
#if __has_builtin(__builtin_amdgcn_exp2f)
  return __builtin_amdgcn_exp2f(x);
#else
  return __expf(x * 0.6931471805599453f);
#endif
}

__device__ __forceinline__ unsigned cvtpk_u32(float a, float b) {
#if __has_builtin(__builtin_amdgcn_cvt_pkrtz)
  return __builtin_bit_cast(unsigned, __builtin_amdgcn_cvt_pkrtz(a, b));
#else
  half2_t h; h.x = (half_t)a; h.y = (half_t)b;
  return __builtin_bit_cast(unsigned, h);
#endif
}

__device__ __forceinline__ float frcp(float x) {
#if __has_builtin(__builtin_amdgcn_rcpf)
  return __builtin_amdgcn_rcpf(x);
#else
  return 1.f / x;
#endif
}

// one kernel converts x, w_qkv, w_proj (contiguous in ws) fp32->fp16
__global__ __launch_bounds__(256) void convert_all(const float4* __restrict__ x,
                                                   const float4* __restrict__ wq,
                                                   const float4* __restrict__ wp,
                                                   half4_t* __restrict__ dst,
                                                   int nx, int nq, int np) {
  int i = blockIdx.x * blockDim.x + threadIdx.x;
  float4 v;
  if (i < nx) v = x[i];
  else if (i < nx + nq) v = wq[i - nx];
  else if (i < nx + nq + np) v = wp[i - nx - nq];
  else return;
  half4_t h;
  h.x = (half_t)v.x; h.y = (half_t)v.y; h.z = (half_t)v.z; h.w = (half_t)v.w;
  dst[i] = h;
}

// C = A[4096][1024] @ Bt[N][1024]^T. 32x32x16 MFMA, BK=64, 128xBN tile, 4 waves.
// MODE 0 (BN=128): qkv epilogue. MODE 1 (BN=64): proj fp32 out.
// XCD-aware block swizzle (grids 768/512, both % 8 == 0).
template <int MODE, int BN>
__global__ __launch_bounds__(256) void gemm32(const half_t* __restrict__ A,
                                              const half_t* __restrict__ Bt,
                                              half_t* __restrict__ q16,
                                              half_t* __restrict__ k16,
                                              half_t* __restrict__ vT16,
                                              float* __restrict__ outp) {
  constexpr int K = 1024;
  constexpr int NT = BN / 64;  // 32x32 n-tiles per wave
  __shared__ __align__(16) half_t a_lds[128 * 64];
  __shared__ __align__(16) half_t b_lds[BN * 64];
  const int t = threadIdx.x;
  const int wave = t >> 6, lane = t & 63;
  const int l31 = lane & 31, hw = lane >> 5;
  const int wm = wave >> 1, wn = wave & 1;

  // XCD swizzle
  const int lin = blockIdx.y * gridDim.x + blockIdx.x;
  const int cpx = (gridDim.x * gridDim.y) >> 3;
  const int nl = (lin & 7) * cpx + (lin >> 3);
  const int bx = nl % gridDim.x, by = nl / gridDim.x;
  const int row0 = by * 128, col0 = bx * BN;

  floatx16 acc[2][NT];
#pragma unroll
  for (int i = 0; i < 2; ++i)
#pragma unroll
    for (int j = 0; j < NT; ++j)
#pragma unroll
      for (int r = 0; r < 16; ++r) acc[i][j][r] = 0.f;

  for (int k0 = 0; k0 < K; k0 += 64) {
    // A: 128 rows x 8 chunks(16B) = 1024 segs, 4/thread
#pragma unroll
    for (int hi = 0; hi < 4; ++hi) {
      int s = t + hi * 256;
      int row = s >> 3, c = s & 7;
      int sc = c ^ (row & 7);
      gl2lds16(A + (size_t)(row0 + row) * K + (k0 + sc * 8), a_lds + (wave * 64 + hi * 256) * 8);
    }
    // B: BN rows x 8 chunks
#pragma unroll
    for (int hi = 0; hi < BN / 32; ++hi) {
      int s = t + hi * 256;
      int row = s >> 3, c = s & 7;
      int sc = c ^ (row & 7);
      gl2lds16(Bt + (size_t)(col0 + row) * K + (k0 + sc * 8), b_lds + (wave * 64 + hi * 256) * 8);
    }
    __syncthreads();
    half8 af[2][4], bf[NT][4];
#pragma unroll
    for (int mt = 0; mt < 2; ++mt) {
      int row = wm * 64 + mt * 32 + l31;
#pragma unroll
      for (int kf = 0; kf < 4; ++kf)
        af[mt][kf] = *(const half8*)(a_lds + row * 64 + ((kf * 2 + hw) ^ (row & 7)) * 8);
    }
#pragma unroll
    for (int nt = 0; nt < NT; ++nt) {
      int row = wn * (BN / 2) + nt * 32 + l31;
#pragma unroll
      for (int kf = 0; kf < 4; ++kf)
        bf[nt][kf] = *(const half8*)(b_lds + row * 64 + ((kf * 2 + hw) ^ (row & 7)) * 8);
    }
#pragma unroll
    for (int kf = 0; kf < 4; ++kf)
#pragma unroll
      for (int mt = 0; mt < 2; ++mt)
#pragma unroll
        for (int nt = 0; nt < NT; ++nt)
          acc[mt][nt] =
              __builtin_amdgcn_mfma_f32_32x32x16_f16(af[mt][kf], bf[nt][kf], acc[mt][nt], 0, 0, 0);
    __syncthreads();
  }

  // C/D 32x32 mapping: col = lane&31, row = (r&3) + 8*(r>>2) + 4*(lane>>5)
  if (MODE == 0) {
    const int which = col0 >> 10;
#pragma unroll
    for (int mt = 0; mt < 2; ++mt)
#pragma unroll
      for (int nt = 0; nt < NT; ++nt) {
        int growb = row0 + wm * 64 + mt * 32;
        int gcol = col0 + wn * (BN / 2) + nt * 32 + l31;
        int hc = gcol & 1023, h = hc >> 6, d = hc & 63;
        if (which == 2) {
#pragma unroll
          for (int rq = 0; rq < 4; ++rq) {
            int grow = growb + 8 * rq + 4 * hw;
            int b = grow >> 11, n0 = grow & 2047;
            int bh = b * NH + h;
            half4_t h4;
            h4.x = (half_t)acc[mt][nt][rq * 4 + 0];
            h4.y = (half_t)acc[mt][nt][rq * 4 + 1];
            h4.z = (half_t)acc[mt][nt][rq * 4 + 2];
            h4.w = (half_t)acc[mt][nt][rq * 4 + 3];
            *(half4_t*)(vT16 + ((size_t)bh * DH + d) * SEQ + n0) = h4;
          }
        } else {
#pragma unroll
          for (int r = 0; r < 16; ++r) {
            int grow = growb + (r & 3) + 8 * (r >> 2) + 4 * hw;
            int b = grow >> 11, n = grow & 2047;
            int bh = b * NH + h;
            float v = acc[mt][nt][r];
            if (which == 0)
              q16[((size_t)bh * SEQ + n) * DH + d] =
                  (half_t)(v * 0.1803368801111204f);  // fold SCALE * log2(e)
            else
              k16[((size_t)bh * SEQ + n) * DH + d] = (half_t)v;
          }
        }
      }
  } else {
#pragma unroll
    for (int mt = 0; mt < 2; ++mt)
#pragma unroll
      for (int nt = 0; nt < NT; ++nt) {
        int growb = row0 + wm * 64 + mt * 32;
        int gcol = col0 + wn * (BN / 2) + nt * 32 + l31;
#pragma unroll
        for (int r = 0; r < 16; ++r) {
          int grow = growb + (r & 3) + 8 * (r >> 2) + 4 * hw;
          outp[(size_t)grow * DIM_ + gcol] = acc[mt][nt][r];
        }
      }
  }
}

// Flash attention, FULL j-range per block (no split -> no combine kernel, no
// opart/psums round-trip). Block = 4 waves x 32 q = 128 q-rows; grid
// 32 bh x 16 qt = 512 = 2 blocks/CU. R6-proven inner loop (all-32x32x16,
// S^T = mfma(K,Q), natural-k PV A-frags via cvt_pkrtz + permlane32_swap).
// Epilogue: psum complete in-block -> normalize locally (per-row denominators
// fetched via 16 broadcast shfls; scl = hwv * rcp(ps)), write fp16 attn16.
__global__ __launch_bounds__(256, 3) void attn_p1(const half_t* __restrict__ q16,
                                                  const half_t* __restrict__ k16,
                                                  const half_t* __restrict__ vT16,
                                                  const float* __restrict__ head_w,
                                                  half_t* __restrict__ attn16) {
  __shared__ __align__(16) half_t k_lds[2][64 * 64];  // [j][d]
  __shared__ __align__(16) half_t v_lds[2][64 * 64];  // vT: [d][j]

  const int t = threadIdx.x;
  const int wave = t >> 6, lane = t & 63;
  const int l31 = lane & 31, hw = lane >> 5;
  const int blk = blockIdx.x;
  const int qt = blk & 15, bh = blk >> 4;
  const int h = bh & 15, b = bh >> 4;
  const half_t* qp = q16 + (size_t)bh * SEQ * DH;
  const half_t* kp = k16 + (size_t)bh * SEQ * DH;
  const half_t* vp = vT16 + (size_t)bh * DH * SEQ;
  const int q0w = qt * 128 + wave * 32;
  constexpr int NJT = SEQ / 64;  // 32

  // staging offsets: 512 segs of 16B (64 rows x 8 chunks), chunk XOR row&7
  const int s0 = t, s1 = t + 256;
  const int r0_ = s0 >> 3, c0_ = (s0 & 7) ^ (r0_ & 7);
  const int r1_ = s1 >> 3, c1_ = (s1 & 7) ^ (r1_ & 7);

  // Q fragments, B-operand 32x32x16: col = l31 = q, k = kf*16 + hw*8 + i
  half8 qf[4];
#pragma unroll
  for (int kf = 0; kf < 4; ++kf)
    qf[kf] = *(const half8*)(qp + (size_t)(q0w + l31) * DH + kf * 16 + hw * 8);

  floatx16 o[2];  // [d-tile]; C/D: col=l31=d, row=(r&3)+8(r>>2)+4hw = q
#pragma unroll
  for (int i = 0; i < 2; ++i)
#pragma unroll
    for (int r = 0; r < 16; ++r) o[i][r] = 0.f;
  float psum = 0.f;

  // prologue: stage tile 0 into buffer 0
  gl2lds16(kp + (size_t)r0_ * DH + c0_ * 8, &k_lds[0][(wave * 64) * 8]);
  gl2lds16(vp + (size_t)r0_ * SEQ + c0_ * 8, &v_lds[0][(wave * 64) * 8]);
  gl2lds16(kp + (size_t)r1_ * DH + c1_ * 8, &k_lds[0][(wave * 64 + 256) * 8]);
  gl2lds16(vp + (size_t)r1_ * SEQ + c1_ * 8, &v_lds[0][(wave * 64 + 256) * 8]);

  int cur = 0;
  for (int jt = 0; jt < NJT; ++jt) {
    __syncthreads();  // publishes buf[cur], protects buf[cur^1]

    if (jt + 1 < NJT) {
      const int j0 = (jt + 1) * 64, nb = cur ^ 1;
      gl2lds16(kp + (size_t)(j0 + r0_) * DH + c0_ * 8, &k_lds[nb][(wave * 64) * 8]);
      gl2lds16(vp + (size_t)r0_ * SEQ + j0 + c0_ * 8, &v_lds[nb][(wave * 64) * 8]);
      gl2lds16(kp + (size_t)(j0 + r1_) * DH + c1_ * 8, &k_lds[nb][(wave * 64 + 256) * 8]);
      gl2lds16(vp + (size_t)r1_ * SEQ + j0 + c1_ * 8, &v_lds[nb][(wave * 64 + 256) * 8]);
    }

    const half_t* kl = k_lds[cur];
    const half_t* vl = v_lds[cur];

    // S^T[j 64][q 32]: A = K (m=j, 2 tiles), B = Q. 8 MFMAs of 32x32x16.
    floatx16 st[2];
#pragma unroll
    for (int m = 0; m < 2; ++m)
#pragma unroll
      for (int r = 0; r < 16; ++r) st[m][r] = 0.f;
    __builtin_amdgcn_s_setprio(1);
#pragma unroll
    for (int kf = 0; kf < 4; ++kf)
#pragma unroll
      for (int m = 0; m < 2; ++m) {
        int row = m * 32 + l31;  // j
        half8 kb = *(const half8*)(kl + row * 64 + ((kf * 2 + hw) ^ (row & 7)) * 8);
        st[m] = __builtin_amdgcn_mfma_f32_32x32x16_f16(kb, qf[kf], st[m], 0, 0, 0);
      }
    __builtin_amdgcn_s_setprio(0);

    // exp2 -> psum + natural-k PV A-frags (cvt_pkrtz + permlane32_swap)
    half8 pa[4];
#pragma unroll
    for (int ks = 0; ks < 4; ++ks) {
      const int m = ks >> 1, rb = (ks & 1) * 8;
      float p0 = fexp2(st[m][rb + 0]);
      float p1 = fexp2(st[m][rb + 1]);
      float p2 = fexp2(st[m][rb + 2]);
      float p3 = fexp2(st[m][rb + 3]);
      float p4 = fexp2(st[m][rb + 4]);
      float p5 = fexp2(st[m][rb + 5]);
      float p6 = fexp2(st[m][rb + 6]);
      float p7 = fexp2(st[m][rb + 7]);
      psum += ((p0 + p1) + (p2 + p3)) + ((p4 + p5) + (p6 + p7));
      unsigned uA = cvtpk_u32(p0, p1);
      unsigned uB = cvtpk_u32(p2, p3);
      unsigned uC = cvtpk_u32(p4, p5);
      unsigned uD = cvtpk_u32(p6, p7);
#if __has_builtin(__builtin_amdgcn_permlane32_swap)
      uint2v sAC = __builtin_bit_cast(uint2v, __builtin_amdgcn_permlane32_swap(uA, uC, false, false));
      uint2v sBD = __builtin_bit_cast(uint2v, __builtin_amdgcn_permlane32_swap(uB, uD, false, false));
      uint4v u;
      u.x = sAC.x; u.y = sBD.x; u.z = sAC.y; u.w = sBD.y;
#else
      unsigned xA = (unsigned)__shfl_xor((int)uA, 32, 64);
      unsigned xB = (unsigned)__shfl_xor((int)uB, 32, 64);
      unsigned xC = (unsigned)__shfl_xor((int)uC, 32, 64);
      unsigned xD = (unsigned)__shfl_xor((int)uD, 32, 64);
      uint4v u;
      u.x = hw ? xC : uA;
      u.y = hw ? xD : uB;
      u.z = hw ? uC : xA;
      u.w = hw ? uD : xB;
#endif
      pa[ks] = __builtin_bit_cast(half8, u);
    }

    // O[q 32][d 64] += P@V. 8 MFMAs; V B-frag natural b128:
    // lane l31 = d-col (vT row), k = j = ks*16 + hw*8 + i -> chunk ks*2+hw.
    __builtin_amdgcn_s_setprio(1);
#pragma unroll
    for (int ks = 0; ks < 4; ++ks)
#pragma unroll
      for (int dt = 0; dt < 2; ++dt) {
        int row = dt * 32 + l31;  // d
        half8 vb = *(const half8*)(vl + row * 64 + ((ks * 2 + hw) ^ (row & 7)) * 8);
        o[dt] = __builtin_amdgcn_mfma_f32_32x32x16_f16(pa[ks], vb, o[dt], 0, 0, 0);
      }
    __builtin_amdgcn_s_setprio(0);
    cur ^= 1;
  }

  // full softmax denominator for q = q0w + l31 (both halves after xor-32)
  psum += __shfl_xor(psum, 32, 64);

  // head weight softmax (per-thread, once)
  float mw = head_w[0];
#pragma unroll
  for (int i = 1; i < NH; ++i) mw = fmaxf(mw, head_w[i]);
  float swd = 0.f;
#pragma unroll
  for (int i = 0; i < NH; ++i) swd += __expf(head_w[i] - mw);
  const float hwv = __expf(head_w[h] - mw) / swd;

  // normalized O -> fp16 attn16; q_row(r) = (r&3)+8(r>>2)+4hw, d = dt*32+l31.
  // per-row denominator lives at lane l31 == q_row: broadcast shfl per r.
#pragma unroll
  for (int r = 0; r < 16; ++r) {
    const int qrow = (r & 3) + 8 * (r >> 2) + 4 * hw;
    const float ps = __shfl(psum, qrow, 64);
    const float scl = hwv * frcp(ps);
    const int n = q0w + qrow;
    const size_t base = ((size_t)(b * SEQ + n)) * DIM_ + h * DH;
#pragma unroll
    for (int dt = 0; dt < 2; ++dt)
      attn16[base + dt * 32 + l31] = (half_t)(o[dt][r] * scl);
  }
}

extern "C" void kernel_launch(void* const* d_in, const int* in_sizes, int n_in,
                              void* d_out, int out_size, void* d_ws, size_t ws_size,
                              hipStream_t stream) {
  const float* x = (const float*)d_in[0];
  const float* w_qkv = (const float*)d_in[1];
  const float* w_proj = (const float*)d_in[2];
  const float* head_w = (const float*)d_in[3];
  float* out = (float*)d_out;

  half_t* x16 = (half_t*)d_ws;                          // 4096*1024
  half_t* wq16 = x16 + (size_t)ROWS * DIM_;             // 3072*1024
  half_t* wp16 = wq16 + (size_t)3 * DIM_ * DIM_;        // 1024*1024
  half_t* q16 = wp16 + (size_t)DIM_ * DIM_;             // [B,H,N,Dh] (scaled by 0.125*log2e)
  half_t* k16 = q16 + (size_t)ROWS * DIM_;              // [B,H,N,Dh]
  half_t* vT16 = k16 + (size_t)ROWS * DIM_;             // [B,H,Dh,N]
  half_t* attn16 = vT16 + (size_t)ROWS * DIM_;          // [B*N, DIM]

  const int nx = ROWS * DIM_ / 4, nq = 3 * DIM_ * DIM_ / 4, np = DIM_ * DIM_ / 4;
  convert_all<<<(nx + nq + np) / 256, 256, 0, stream>>>((const float4*)x, (const float4*)w_qkv,
                                                        (const float4*)w_proj, (half4_t*)x16,
                                                        nx, nq, np);

  gemm32<0, 128><<<dim3(24, 32), 256, 0, stream>>>(x16, wq16, q16, k16, vT16, nullptr);
  attn_p1<<<32 * 16, 256, 0, stream>>>(q16, k16, vT16, head_w, attn16);
  gemm32<1, 64><<<dim3(16, 32), 256, 0, stream>>>(attn16, wp16, nullptr, nullptr, nullptr, out);
}

// Round 12
// 176.460 us; speedup vs baseline: 1.2036x; 1.0278x over previous
//
#include <hip/hip_runtime.h>

typedef _Float16 half_t;
typedef _Float16 half8 __attribute__((ext_vector_type(8)));
typedef _Float16 half4_t __attribute__((ext_vector_type(4)));
typedef _Float16 half2_t __attribute__((ext_vector_type(2)));
typedef float floatx4 __attribute__((ext_vector_type(4)));
typedef float floatx16 __attribute__((ext_vector_type(16)));
typedef unsigned int uint4v __attribute__((ext_vector_type(4)));
typedef unsigned int uint2v __attribute__((ext_vector_type(2)));

#define B_SZ 2
#define SEQ 2048
#define DIM_ 1024
#define NH 16
#define DH 64
#define ROWS (B_SZ * SEQ)   // 4096

// async global->LDS, 16B per lane; LDS dest = wave-uniform base + lane*16
__device__ __forceinline__ void gl2lds16(const void* g, void* l) {
  __builtin_amdgcn_global_load_lds((const __attribute__((address_space(1))) unsigned int*)g,
                                   (__attribute__((address_space(3))) unsigned int*)l, 16, 0, 0);
}

// exp2 (single v_exp_f32; log2(e) folded into q scale at GEMM epilogue)
__device__ __forceinline__ float fexp2(float x) {
#if __has_builtin(__builtin_amdgcn_exp2f)
  return __builtin_amdgcn_exp2f(x);
#else
  return __expf(x * 0.6931471805599453f);
#endif
}

__device__ __forceinline__ unsigned cvtpk_u32(float a, float b) {
#if __has_builtin(__builtin_amdgcn_cvt_pkrtz)
  return __builtin_bit_cast(unsigned, __builtin_amdgcn_cvt_pkrtz(a, b));
#else
  half2_t h; h.x = (half_t)a; h.y = (half_t)b;
  return __builtin_bit_cast(unsigned, h);
#endif
}

__device__ __forceinline__ float frcp(float x) {
#if __has_builtin(__builtin_amdgcn_rcpf)
  return __builtin_amdgcn_rcpf(x);
#else
  return 1.f / x;
#endif
}

// one kernel converts x, w_qkv, w_proj (contiguous in ws) fp32->fp16
__global__ __launch_bounds__(256) void convert_all(const float4* __restrict__ x,
                                                   const float4* __restrict__ wq,
                                                   const float4* __restrict__ wp,
                                                   half4_t* __restrict__ dst,
                                                   int nx, int nq, int np) {
  int i = blockIdx.x * blockDim.x + threadIdx.x;
  float4 v;
  if (i < nx) v = x[i];
  else if (i < nx + nq) v = wq[i - nx];
  else if (i < nx + nq + np) v = wp[i - nx - nq];
  else return;
  half4_t h;
  h.x = (half_t)v.x; h.y = (half_t)v.y; h.z = (half_t)v.z; h.w = (half_t)v.w;
  dst[i] = h;
}

// C = A[4096][1024] @ Bt[N][1024]^T. 32x32x16 MFMA, BK=64, 128xBN tile, 4 waves.
// MODE 0 (BN=128): qkv epilogue. MODE 1 (BN=64): proj fp32 out.
// XCD-aware block swizzle (grids 768/512, both % 8 == 0).
template <int MODE, int BN>
__global__ __launch_bounds__(256) void gemm32(const half_t* __restrict__ A,
                                              const half_t* __restrict__ Bt,
                                              half_t* __restrict__ q16,
                                              half_t* __restrict__ k16,
                                              half_t* __restrict__ vT16,
                                              float* __restrict__ outp) {
  constexpr int K = 1024;
  constexpr int NT = BN / 64;  // 32x32 n-tiles per wave
  __shared__ __align__(16) half_t a_lds[128 * 64];
  __shared__ __align__(16) half_t b_lds[BN * 64];
  const int t = threadIdx.x;
  const int wave = t >> 6, lane = t & 63;
  const int l31 = lane & 31, hw = lane >> 5;
  const int wm = wave >> 1, wn = wave & 1;

  // XCD swizzle
  const int lin = blockIdx.y * gridDim.x + blockIdx.x;
  const int cpx = (gridDim.x * gridDim.y) >> 3;
  const int nl = (lin & 7) * cpx + (lin >> 3);
  const int bx = nl % gridDim.x, by = nl / gridDim.x;
  const int row0 = by * 128, col0 = bx * BN;

  floatx16 acc[2][NT];
#pragma unroll
  for (int i = 0; i < 2; ++i)
#pragma unroll
    for (int j = 0; j < NT; ++j)
#pragma unroll
      for (int r = 0; r < 16; ++r) acc[i][j][r] = 0.f;

  for (int k0 = 0; k0 < K; k0 += 64) {
    // A: 128 rows x 8 chunks(16B) = 1024 segs, 4/thread
#pragma unroll
    for (int hi = 0; hi < 4; ++hi) {
      int s = t + hi * 256;
      int row = s >> 3, c = s & 7;
      int sc = c ^ (row & 7);
      gl2lds16(A + (size_t)(row0 + row) * K + (k0 + sc * 8), a_lds + (wave * 64 + hi * 256) * 8);
    }
    // B: BN rows x 8 chunks
#pragma unroll
    for (int hi = 0; hi < BN / 32; ++hi) {
      int s = t + hi * 256;
      int row = s >> 3, c = s & 7;
      int sc = c ^ (row & 7);
      gl2lds16(Bt + (size_t)(col0 + row) * K + (k0 + sc * 8), b_lds + (wave * 64 + hi * 256) * 8);
    }
    __syncthreads();
    half8 af[2][4], bf[NT][4];
#pragma unroll
    for (int mt = 0; mt < 2; ++mt) {
      int row = wm * 64 + mt * 32 + l31;
#pragma unroll
      for (int kf = 0; kf < 4; ++kf)
        af[mt][kf] = *(const half8*)(a_lds + row * 64 + ((kf * 2 + hw) ^ (row & 7)) * 8);
    }
#pragma unroll
    for (int nt = 0; nt < NT; ++nt) {
      int row = wn * (BN / 2) + nt * 32 + l31;
#pragma unroll
      for (int kf = 0; kf < 4; ++kf)
        bf[nt][kf] = *(const half8*)(b_lds + row * 64 + ((kf * 2 + hw) ^ (row & 7)) * 8);
    }
#pragma unroll
    for (int kf = 0; kf < 4; ++kf)
#pragma unroll
      for (int mt = 0; mt < 2; ++mt)
#pragma unroll
        for (int nt = 0; nt < NT; ++nt)
          acc[mt][nt] =
              __builtin_amdgcn_mfma_f32_32x32x16_f16(af[mt][kf], bf[nt][kf], acc[mt][nt], 0, 0, 0);
    __syncthreads();
  }

  // C/D 32x32 mapping: col = lane&31, row = (r&3) + 8*(r>>2) + 4*(lane>>5)
  if (MODE == 0) {
    const int which = col0 >> 10;
#pragma unroll
    for (int mt = 0; mt < 2; ++mt)
#pragma unroll
      for (int nt = 0; nt < NT; ++nt) {
        int growb = row0 + wm * 64 + mt * 32;
        int gcol = col0 + wn * (BN / 2) + nt * 32 + l31;
        int hc = gcol & 1023, h = hc >> 6, d = hc & 63;
        if (which == 2) {
#pragma unroll
          for (int rq = 0; rq < 4; ++rq) {
            int grow = growb + 8 * rq + 4 * hw;
            int b = grow >> 11, n0 = grow & 2047;
            int bh = b * NH + h;
            half4_t h4;
            h4.x = (half_t)acc[mt][nt][rq * 4 + 0];
            h4.y = (half_t)acc[mt][nt][rq * 4 + 1];
            h4.z = (half_t)acc[mt][nt][rq * 4 + 2];
            h4.w = (half_t)acc[mt][nt][rq * 4 + 3];
            *(half4_t*)(vT16 + ((size_t)bh * DH + d) * SEQ + n0) = h4;
          }
        } else {
#pragma unroll
          for (int r = 0; r < 16; ++r) {
            int grow = growb + (r & 3) + 8 * (r >> 2) + 4 * hw;
            int b = grow >> 11, n = grow & 2047;
            int bh = b * NH + h;
            float v = acc[mt][nt][r];
            if (which == 0)
              q16[((size_t)bh * SEQ + n) * DH + d] =
                  (half_t)(v * 0.1803368801111204f);  // fold SCALE * log2(e)
            else
              k16[((size_t)bh * SEQ + n) * DH + d] = (half_t)v;
          }
        }
      }
  } else {
#pragma unroll
    for (int mt = 0; mt < 2; ++mt)
#pragma unroll
      for (int nt = 0; nt < NT; ++nt) {
        int growb = row0 + wm * 64 + mt * 32;
        int gcol = col0 + wn * (BN / 2) + nt * 32 + l31;
#pragma unroll
        for (int r = 0; r < 16; ++r) {
          int grow = growb + (r & 3) + 8 * (r >> 2) + 4 * hw;
          outp[(size_t)grow * DIM_ + gcol] = acc[mt][nt][r];
        }
      }
  }
}

// Flash attention, full j-range, fused normalize (R11 structure) +
// 3-buffer / 2-deep-prefetch staging with COUNTED vmcnt (T4): each wave waits
// only for its own tile-t+1 loads (vmcnt(4)) while tile-t+2's 4 loads stay in
// flight across the raw s_barrier -- removes the per-tile vmcnt(0) drain that
// profiled as the synchronized stall (all pipes <=40% for 8 rounds).
// Hazards: buffer written at jt+2 was last read at jt-1 (barrier separates);
// vmcnt retires in issue order so the early Q loads are covered by the count.
__global__ __launch_bounds__(256, 3) void attn_p1(const half_t* __restrict__ q16,
                                                  const half_t* __restrict__ k16,
                                                  const half_t* __restrict__ vT16,
                                                  const float* __restrict__ head_w,
                                                  half_t* __restrict__ attn16) {
  __shared__ __align__(16) half_t k_lds[3][64 * 64];  // [buf][j][d]
  __shared__ __align__(16) half_t v_lds[3][64 * 64];  // [buf] vT: [d][j]

  const int t = threadIdx.x;
  const int wave = t >> 6, lane = t & 63;
  const int l31 = lane & 31, hw = lane >> 5;
  const int blk = blockIdx.x;
  const int qt = blk & 15, bh = blk >> 4;
  const int h = bh & 15, b = bh >> 4;
  const half_t* qp = q16 + (size_t)bh * SEQ * DH;
  const half_t* kp = k16 + (size_t)bh * SEQ * DH;
  const half_t* vp = vT16 + (size_t)bh * DH * SEQ;
  const int q0w = qt * 128 + wave * 32;
  constexpr int NJT = SEQ / 64;  // 32

  // staging offsets: 512 segs of 16B (64 rows x 8 chunks), chunk XOR row&7
  const int s0 = t, s1 = t + 256;
  const int r0_ = s0 >> 3, c0_ = (s0 & 7) ^ (r0_ & 7);
  const int r1_ = s1 >> 3, c1_ = (s1 & 7) ^ (r1_ & 7);

  // Q fragments, B-operand 32x32x16: col = l31 = q, k = kf*16 + hw*8 + i
  half8 qf[4];
#pragma unroll
  for (int kf = 0; kf < 4; ++kf)
    qf[kf] = *(const half8*)(qp + (size_t)(q0w + l31) * DH + kf * 16 + hw * 8);

  floatx16 o[2];  // [d-tile]; C/D: col=l31=d, row=(r&3)+8(r>>2)+4hw = q
#pragma unroll
  for (int i = 0; i < 2; ++i)
#pragma unroll
    for (int r = 0; r < 16; ++r) o[i][r] = 0.f;
  float psum = 0.f;

  // stage helper offsets (elements) per buffer
  const int kdst0 = (wave * 64) * 8, kdst1 = (wave * 64 + 256) * 8;

  // prologue: stage tiles 0 and 1 into buffers 0 and 1 (8 loads in flight)
  {
    gl2lds16(kp + (size_t)r0_ * DH + c0_ * 8, &k_lds[0][kdst0]);
    gl2lds16(vp + (size_t)r0_ * SEQ + c0_ * 8, &v_lds[0][kdst0]);
    gl2lds16(kp + (size_t)r1_ * DH + c1_ * 8, &k_lds[0][kdst1]);
    gl2lds16(vp + (size_t)r1_ * SEQ + c1_ * 8, &v_lds[0][kdst1]);
    const int j1 = 64;
    gl2lds16(kp + (size_t)(j1 + r0_) * DH + c0_ * 8, &k_lds[1][kdst0]);
    gl2lds16(vp + (size_t)r0_ * SEQ + j1 + c0_ * 8, &v_lds[1][kdst0]);
    gl2lds16(kp + (size_t)(j1 + r1_) * DH + c1_ * 8, &k_lds[1][kdst1]);
    gl2lds16(vp + (size_t)r1_ * SEQ + j1 + c1_ * 8, &v_lds[1][kdst1]);
  }
  __builtin_amdgcn_sched_barrier(0);
  asm volatile("s_waitcnt vmcnt(4)" ::: "memory");  // tile 0 landed
  __builtin_amdgcn_sched_barrier(0);
  __builtin_amdgcn_s_barrier();
  __builtin_amdgcn_sched_barrier(0);

  int cur = 0;
  for (int jt = 0; jt < NJT; ++jt) {
    // prefetch tile jt+2 into buffer (cur+2)%3 (last read at jt-1; barrier'd)
    if (jt + 2 < NJT) {
      int nb = cur + 2; if (nb >= 3) nb -= 3;
      const int j0 = (jt + 2) * 64;
      gl2lds16(kp + (size_t)(j0 + r0_) * DH + c0_ * 8, &k_lds[nb][kdst0]);
      gl2lds16(vp + (size_t)r0_ * SEQ + j0 + c0_ * 8, &v_lds[nb][kdst0]);
      gl2lds16(kp + (size_t)(j0 + r1_) * DH + c1_ * 8, &k_lds[nb][kdst1]);
      gl2lds16(vp + (size_t)r1_ * SEQ + j0 + c1_ * 8, &v_lds[nb][kdst1]);
    }

    const half_t* kl = k_lds[cur];
    const half_t* vl = v_lds[cur];

    // S^T[j 64][q 32]: A = K (m=j, 2 tiles), B = Q. 8 MFMAs of 32x32x16.
    floatx16 st[2];
#pragma unroll
    for (int m = 0; m < 2; ++m)
#pragma unroll
      for (int r = 0; r < 16; ++r) st[m][r] = 0.f;
    __builtin_amdgcn_s_setprio(1);
#pragma unroll
    for (int kf = 0; kf < 4; ++kf)
#pragma unroll
      for (int m = 0; m < 2; ++m) {
        int row = m * 32 + l31;  // j
        half8 kb = *(const half8*)(kl + row * 64 + ((kf * 2 + hw) ^ (row & 7)) * 8);
        st[m] = __builtin_amdgcn_mfma_f32_32x32x16_f16(kb, qf[kf], st[m], 0, 0, 0);
      }
    __builtin_amdgcn_s_setprio(0);

    // exp2 -> psum + natural-k PV A-frags (cvt_pkrtz + permlane32_swap)
    half8 pa[4];
#pragma unroll
    for (int ks = 0; ks < 4; ++ks) {
      const int m = ks >> 1, rb = (ks & 1) * 8;
      float p0 = fexp2(st[m][rb + 0]);
      float p1 = fexp2(st[m][rb + 1]);
      float p2 = fexp2(st[m][rb + 2]);
      float p3 = fexp2(st[m][rb + 3]);
      float p4 = fexp2(st[m][rb + 4]);
      float p5 = fexp2(st[m][rb + 5]);
      float p6 = fexp2(st[m][rb + 6]);
      float p7 = fexp2(st[m][rb + 7]);
      psum += ((p0 + p1) + (p2 + p3)) + ((p4 + p5) + (p6 + p7));
      unsigned uA = cvtpk_u32(p0, p1);
      unsigned uB = cvtpk_u32(p2, p3);
      unsigned uC = cvtpk_u32(p4, p5);
      unsigned uD = cvtpk_u32(p6, p7);
#if __has_builtin(__builtin_amdgcn_permlane32_swap)
      uint2v sAC = __builtin_bit_cast(uint2v, __builtin_amdgcn_permlane32_swap(uA, uC, false, false));
      uint2v sBD = __builtin_bit_cast(uint2v, __builtin_amdgcn_permlane32_swap(uB, uD, false, false));
      uint4v u;
      u.x = sAC.x; u.y = sBD.x; u.z = sAC.y; u.w = sBD.y;
#else
      unsigned xA = (unsigned)__shfl_xor((int)uA, 32, 64);
      unsigned xB = (unsigned)__shfl_xor((int)uB, 32, 64);
      unsigned xC = (unsigned)__shfl_xor((int)uC, 32, 64);
      unsigned xD = (unsigned)__shfl_xor((int)uD, 32, 64);
      uint4v u;
      u.x = hw ? xC : uA;
      u.y = hw ? xD : uB;
      u.z = hw ? uC : xA;
      u.w = hw ? uD : xB;
#endif
      pa[ks] = __builtin_bit_cast(half8, u);
    }

    // O[q 32][d 64] += P@V. 8 MFMAs; V B-frag natural b128.
    __builtin_amdgcn_s_setprio(1);
#pragma unroll
    for (int ks = 0; ks < 4; ++ks)
#pragma unroll
      for (int dt = 0; dt < 2; ++dt) {
        int row = dt * 32 + l31;  // d
        half8 vb = *(const half8*)(vl + row * 64 + ((ks * 2 + hw) ^ (row & 7)) * 8);
        o[dt] = __builtin_amdgcn_mfma_f32_32x32x16_f16(pa[ks], vb, o[dt], 0, 0, 0);
      }
    __builtin_amdgcn_s_setprio(0);

    // counted wait + raw barrier: tile jt+1 guaranteed landed in all waves;
    // tile jt+2's 4 loads stay in flight. Peeled: vmcnt(0) at jt==NJT-2,
    // nothing after the last tile.
    if (jt + 2 < NJT) {
      __builtin_amdgcn_sched_barrier(0);
      asm volatile("s_waitcnt vmcnt(4)" ::: "memory");
      __builtin_amdgcn_sched_barrier(0);
      __builtin_amdgcn_s_barrier();
      __builtin_amdgcn_sched_barrier(0);
    } else if (jt + 1 < NJT) {
      __builtin_amdgcn_sched_barrier(0);
      asm volatile("s_waitcnt vmcnt(0)" ::: "memory");
      __builtin_amdgcn_sched_barrier(0);
      __builtin_amdgcn_s_barrier();
      __builtin_amdgcn_sched_barrier(0);
    }
    cur = (cur == 2) ? 0 : cur + 1;
  }

  // full softmax denominator for q = q0w + l31 (both halves after xor-32)
  psum += __shfl_xor(psum, 32, 64);

  // head weight softmax (per-thread, once)
  float mw = head_w[0];
#pragma unroll
  for (int i = 1; i < NH; ++i) mw = fmaxf(mw, head_w[i]);
  float swd = 0.f;
#pragma unroll
  for (int i = 0; i < NH; ++i) swd += __expf(head_w[i] - mw);
  const float hwv = __expf(head_w[h] - mw) / swd;

  // normalized O -> fp16 attn16; q_row(r) = (r&3)+8(r>>2)+4hw, d = dt*32+l31.
#pragma unroll
  for (int r = 0; r < 16; ++r) {
    const int qrow = (r & 3) + 8 * (r >> 2) + 4 * hw;
    const float ps = __shfl(psum, qrow, 64);
    const float scl = hwv * frcp(ps);
    const int n = q0w + qrow;
    const size_t base = ((size_t)(b * SEQ + n)) * DIM_ + h * DH;
#pragma unroll
    for (int dt = 0; dt < 2; ++dt)
      attn16[base + dt * 32 + l31] = (half_t)(o[dt][r] * scl);
  }
}

extern "C" void kernel_launch(void* const* d_in, const int* in_sizes, int n_in,
                              void* d_out, int out_size, void* d_ws, size_t ws_size,
                              hipStream_t stream) {
  const float* x = (const float*)d_in[0];
  const float* w_qkv = (const float*)d_in[1];
  const float* w_proj = (const float*)d_in[2];
  const float* head_w = (const float*)d_in[3];
  float* out = (float*)d_out;

  half_t* x16 = (half_t*)d_ws;                          // 4096*1024
  half_t* wq16 = x16 + (size_t)ROWS * DIM_;             // 3072*1024
  half_t* wp16 = wq16 + (size_t)3 * DIM_ * DIM_;        // 1024*1024
  half_t* q16 = wp16 + (size_t)DIM_ * DIM_;             // [B,H,N,Dh] (scaled by 0.125*log2e)
  half_t* k16 = q16 + (size_t)ROWS * DIM_;              // [B,H,N,Dh]
  half_t* vT16 = k16 + (size_t)ROWS * DIM_;             // [B,H,Dh,N]
  half_t* attn16 = vT16 + (size_t)ROWS * DIM_;          // [B*N, DIM]

  const int nx = ROWS * DIM_ / 4, nq = 3 * DIM_ * DIM_ / 4, np = DIM_ * DIM_ / 4;
  convert_all<<<(nx + nq + np) / 256, 256, 0, stream>>>((const float4*)x, (const float4*)w_qkv,
                                                        (const float4*)w_proj, (half4_t*)x16,
                                                        nx, nq, np);

  gemm32<0, 128><<<dim3(24, 32), 256, 0, stream>>>(x16, wq16, q16, k16, vT16, nullptr);
  attn_p1<<<32 * 16, 256, 0, stream>>>(q16, k16, vT16, head_w, attn16);
  gemm32<1, 64><<<dim3(16, 32), 256, 0, stream>>>(attn16, wp16, nullptr, nullptr, nullptr, out);
}